// Round 1
// baseline (767.547 us; speedup 1.0000x reference)
//
#include <hip/hip_runtime.h>

// Shapes fixed by setup_inputs(): B=4, L=1024, E=1024, H=16, D=64, W=128
#define BB 4
#define LL 1024
#define EE 1024
#define HH 16
#define DD 64

typedef __attribute__((ext_vector_type(8))) short short8;
typedef __attribute__((ext_vector_type(4))) float floatx4;

__device__ __forceinline__ float bf2f(short s) {
    union { unsigned u; float f; } c;
    c.u = ((unsigned)(unsigned short)s) << 16;
    return c.f;
}
__device__ __forceinline__ short f2bf(float f) {
    union { float f; unsigned u; } c; c.f = f;
    unsigned r = c.u + 0x7fffu + ((c.u >> 16) & 1u);
    return (short)(r >> 16);
}

__device__ __forceinline__ void async_copy16(const void* g, void* l) {
    __builtin_amdgcn_global_load_lds(
        (const __attribute__((address_space(1))) unsigned int*)g,
        (__attribute__((address_space(3))) unsigned int*)l, 16, 0, 0);
}

// ---------------------------------------------------------------- convert
__global__ __launch_bounds__(256) void cvt_kernel(const float* __restrict__ in,
                                                  short* __restrict__ out, int n4) {
    int i = blockIdx.x * 256 + threadIdx.x;
    if (i < n4) {
        float4 v = ((const float4*)in)[i];
        unsigned long long u =
              (unsigned long long)(unsigned short)f2bf(v.x)
            | ((unsigned long long)(unsigned short)f2bf(v.y) << 16)
            | ((unsigned long long)(unsigned short)f2bf(v.z) << 32)
            | ((unsigned long long)(unsigned short)f2bf(v.w) << 48);
        ((unsigned long long*)out)[i] = u;
    }
}

// ---------------------------------------------------------------- GEMM (NT)
// C[m,n] = sum_k A[m,k]*B[n,k] + bias[n]; A:[M,K] bf16, B:[N,K] bf16.
// 128x128 tile, BK=32, 256 thr (4 waves, 2x2 of 64x64), m97 structure.
template<bool RELU, bool OUT_BF16>
__global__ __launch_bounds__(256) void gemm_bt(
    const short* __restrict__ A, const short* __restrict__ Bw,
    const float* __restrict__ bias,
    float* __restrict__ Cf, short* __restrict__ Cb,
    int M, int N, int K)
{
    __shared__ short As[4096];
    __shared__ short Bs[4096];
    const int tid  = threadIdx.x;
    const int wave = tid >> 6, lane = tid & 63;
    const int m0 = blockIdx.x * 128, n0 = blockIdx.y * 128;
    const int wm = (wave & 1) * 64, wn = (wave >> 1) * 64;

    floatx4 acc[4][4];
#pragma unroll
    for (int i = 0; i < 4; ++i)
#pragma unroll
        for (int j = 0; j < 4; ++j) acc[i][j] = (floatx4){0.f, 0.f, 0.f, 0.f};

    const int srow = tid >> 2;
    const int skc  = (tid & 3) * 8;
    const short* ga0 = A  + (size_t)(m0 + srow) * K + skc;
    const short* ga1 = A  + (size_t)(m0 + 64 + srow) * K + skc;
    const short* gb0 = Bw + (size_t)(n0 + srow) * K + skc;
    const short* gb1 = Bw + (size_t)(n0 + 64 + srow) * K + skc;
    short* la0 = As + wave * 512;
    short* la1 = As + 2048 + wave * 512;
    short* lb0 = Bs + wave * 512;
    short* lb1 = Bs + 2048 + wave * 512;

    const int fr = lane & 15, fk = (lane >> 4) * 8;
    const int kiters = K >> 5;
    for (int kt = 0; kt < kiters; ++kt) {
        async_copy16(ga0, la0);
        async_copy16(ga1, la1);
        async_copy16(gb0, lb0);
        async_copy16(gb1, lb1);
        ga0 += 32; ga1 += 32; gb0 += 32; gb1 += 32;
        __syncthreads();
        short8 af[4], bfr[4];
#pragma unroll
        for (int i = 0; i < 4; ++i) {
            af[i]  = *(const short8*)&As[(wm + i * 16 + fr) * 32 + fk];
            bfr[i] = *(const short8*)&Bs[(wn + i * 16 + fr) * 32 + fk];
        }
#pragma unroll
        for (int i = 0; i < 4; ++i)
#pragma unroll
            for (int j = 0; j < 4; ++j)
                acc[i][j] = __builtin_amdgcn_mfma_f32_16x16x32_bf16(af[i], bfr[j], acc[i][j], 0, 0, 0);
        __syncthreads();
    }

    const int cc = lane & 15;
    const int rbase = (lane >> 4) * 4;
#pragma unroll
    for (int j = 0; j < 4; ++j) {
        int col = n0 + wn + j * 16 + cc;
        float bv = bias[col];
#pragma unroll
        for (int i = 0; i < 4; ++i) {
            int row = m0 + wm + i * 16 + rbase;
#pragma unroll
            for (int r = 0; r < 4; ++r) {
                float v = acc[i][j][r] + bv;
                if (RELU) v = fmaxf(v, 0.0f);
                if (OUT_BF16) Cb[(size_t)(row + r) * N + col] = f2bf(v);
                else          Cf[(size_t)(row + r) * N + col] = v;
            }
        }
    }
}

// ---------------------------------------------------------------- LayerNorm
// out = LN(a + b) * g + beta ; row-per-block, E=1024, 256 thr x 4 elems.
__global__ __launch_bounds__(256) void ln_kernel(
    const float* __restrict__ xa, const float* __restrict__ xb,
    const float* __restrict__ g, const float* __restrict__ beta,
    float* __restrict__ outf, short* __restrict__ outb)
{
    const int row = blockIdx.x;
    const int tid = threadIdx.x;
    float4 va = ((const float4*)(xa + (size_t)row * EE))[tid];
    float4 vb = ((const float4*)(xb + (size_t)row * EE))[tid];
    float v0 = va.x + vb.x, v1 = va.y + vb.y, v2 = va.z + vb.z, v3 = va.w + vb.w;
    float s  = v0 + v1 + v2 + v3;
    float ss = v0 * v0 + v1 * v1 + v2 * v2 + v3 * v3;
#pragma unroll
    for (int o = 1; o < 64; o <<= 1) { s += __shfl_xor(s, o); ss += __shfl_xor(ss, o); }
    __shared__ float red[8];
    if ((tid & 63) == 0) { red[(tid >> 6) * 2] = s; red[(tid >> 6) * 2 + 1] = ss; }
    __syncthreads();
    s  = red[0] + red[2] + red[4] + red[6];
    ss = red[1] + red[3] + red[5] + red[7];
    float mean = s * (1.0f / EE);
    float var  = ss * (1.0f / EE) - mean * mean;
    float rstd = rsqrtf(var + 1e-5f);
    float4 vg = ((const float4*)g)[tid];
    float4 vt = ((const float4*)beta)[tid];
    float o0 = (v0 - mean) * rstd * vg.x + vt.x;
    float o1 = (v1 - mean) * rstd * vg.y + vt.y;
    float o2 = (v2 - mean) * rstd * vg.z + vt.z;
    float o3 = (v3 - mean) * rstd * vg.w + vt.w;
    if (outf) ((float4*)(outf + (size_t)row * EE))[tid] = make_float4(o0, o1, o2, o3);
    if (outb) {
        unsigned long long u =
              (unsigned long long)(unsigned short)f2bf(o0)
            | ((unsigned long long)(unsigned short)f2bf(o1) << 16)
            | ((unsigned long long)(unsigned short)f2bf(o2) << 32)
            | ((unsigned long long)(unsigned short)f2bf(o3) << 48);
        ((unsigned long long*)(outb + (size_t)row * EE))[tid] = u;
    }
}

// ---------------------------------------------------------------- attention
// Banded (|i-j|<=128) attention, one (b,h,32-row tile) per block, 512 thr.
// K band in LDS (stride 66 -> conflict-free), Q fp32 in LDS (broadcast),
// V streamed from global (L1/L2 resident). Per-wave row softmax.
__global__ __launch_bounds__(512) void attn_kernel(
    const short* __restrict__ qkv,   // [4096, 3072] bf16 bits
    short* __restrict__ ctx,         // [4096, 1024] bf16 bits
    float* __restrict__ attnW)       // [B,1024,1024] fp32, pre-zeroed
{
    const int i0 = blockIdx.x * 32;
    const int h  = blockIdx.y;
    const int b  = blockIdx.z;
    const int jb0 = i0 - 128;        // may be negative (masked)

    __shared__ short Ks[288 * 66];   // 38,016 B
    __shared__ float Qs[32 * 64];    //  8,192 B
    __shared__ float Ps[8][320];     // 10,240 B  (per-wave row probs)

    const int tid = threadIdx.x, wave = tid >> 6, lane = tid & 63;
    const short* qbase = qkv + ((size_t)b * LL) * 3072 + (size_t)h * DD;
    const short* vbase = qbase + 2048;

    // stage Q (fp32)
    for (int e = tid; e < 32 * 64; e += 512) {
        int r = e >> 6, d = e & 63;
        Qs[e] = bf2f(qbase[(size_t)(i0 + r) * 3072 + d]);
    }
    // stage K band: 288 rows x 64 d, zero-filled out of range
    {
        const int jr = tid >> 5, dp = tid & 31;
#pragma unroll
        for (int rr = 0; rr < 18; ++rr) {
            int j = rr * 16 + jr;
            int jg = jb0 + j;
            unsigned kk = 0u;
            if ((unsigned)jg < 1024u)
                kk = *(const unsigned*)&qbase[(size_t)jg * 3072 + 1024 + dp * 2];
            *(unsigned*)&Ks[j * 66 + dp * 2] = kk;
        }
    }
    __syncthreads();

    for (int rr = 0; rr < 4; ++rr) {
        const int r = wave * 4 + rr;
        const int i = i0 + r;
        int off[5]; bool val[5];
        float dot[5] = {0.f, 0.f, 0.f, 0.f, 0.f};
#pragma unroll
        for (int jt = 0; jt < 5; ++jt) {
            int jo = jt * 64 + lane;          // window offset [0,320)
            int jl = r + jo;                  // block-local K row
            off[jt] = (jl < 288 ? jl : 287) * 66;
            int jg = jb0 + jl;                // global col = i - 128 + jo
            val[jt] = (jo <= 256) && ((unsigned)jg < 1024u);
        }
        const float* qrow = Qs + r * 64;
#pragma unroll 4
        for (int d0 = 0; d0 < 64; d0 += 2) {
            float q0 = qrow[d0], q1 = qrow[d0 + 1];
#pragma unroll
            for (int jt = 0; jt < 5; ++jt) {
                unsigned kk = *(const unsigned*)&Ks[off[jt] + d0];
                dot[jt] = fmaf(q0, bf2f((short)(kk & 0xffff)), dot[jt]);
                dot[jt] = fmaf(q1, bf2f((short)(kk >> 16)), dot[jt]);
            }
        }
        float m = -1e30f, sv[5];
#pragma unroll
        for (int jt = 0; jt < 5; ++jt) {
            sv[jt] = val[jt] ? dot[jt] * 0.125f : -1e30f;
            m = fmaxf(m, sv[jt]);
        }
#pragma unroll
        for (int o = 32; o; o >>= 1) m = fmaxf(m, __shfl_xor(m, o));
        float l = 0.f, p[5];
#pragma unroll
        for (int jt = 0; jt < 5; ++jt) { p[jt] = __expf(sv[jt] - m); l += p[jt]; }
#pragma unroll
        for (int o = 32; o; o >>= 1) l += __shfl_xor(l, o);
        float inv = 1.0f / l;

        float* prow = attnW + ((size_t)b * LL + i) * LL;
#pragma unroll
        for (int jt = 0; jt < 5; ++jt) {
            int jo = jt * 64 + lane;
            float pv = p[jt] * inv;
            Ps[wave][jo] = val[jt] ? pv : 0.0f;
            if (val[jt]) atomicAdd(prow + (jb0 + r + jo), pv * (1.0f / HH));
        }

        // ctx: lane = (jh, dpair); V from global; combine halves via shfl
        const int jh = lane >> 5, dp = lane & 31;
        float c0 = 0.f, c1 = 0.f;
#pragma unroll 4
        for (int jj = 0; jj < 129; ++jj) {
            int jo = jh * 129 + jj;           // [0,257], jo=257 has p=0
            int jg = i - 128 + jo;
            float pv = Ps[wave][jo];
            unsigned vv = 0u;
            if ((unsigned)jg < 1024u && jo <= 256)
                vv = *(const unsigned*)&vbase[(size_t)jg * 3072 + dp * 2];
            c0 = fmaf(pv, bf2f((short)(vv & 0xffff)), c0);
            c1 = fmaf(pv, bf2f((short)(vv >> 16)), c1);
        }
        c0 += __shfl_xor(c0, 32);
        c1 += __shfl_xor(c1, 32);
        if (lane < 32) {
            unsigned o = (unsigned)(unsigned short)f2bf(c0)
                       | ((unsigned)(unsigned short)f2bf(c1) << 16);
            *(unsigned*)&ctx[((size_t)b * LL + i) * EE + (size_t)h * DD + dp * 2] = o;
        }
    }
}

// ---------------------------------------------------------------- launch
extern "C" void kernel_launch(void* const* d_in, const int* in_sizes, int n_in,
                              void* d_out, int out_size, void* d_ws, size_t ws_size,
                              hipStream_t stream) {
    const float* x    = (const float*)d_in[0];
    const float* wqkv = (const float*)d_in[1];
    const float* bqkv = (const float*)d_in[2];
    const float* wo   = (const float*)d_in[3];
    const float* bo   = (const float*)d_in[4];
    const float* g1   = (const float*)d_in[5];
    const float* be1  = (const float*)d_in[6];
    const float* w1   = (const float*)d_in[7];
    const float* bb1  = (const float*)d_in[8];
    const float* w2   = (const float*)d_in[9];
    const float* bb2  = (const float*)d_in[10];
    const float* g2   = (const float*)d_in[11];
    const float* be2  = (const float*)d_in[12];
    // d_in[13]=n_head(16), d_in[14]=window_size(128): fixed by problem shapes.

    char* ws = (char*)d_ws;
    size_t off = 0;
    auto take = [&](size_t bytes) {
        void* p = ws + off;
        off += (bytes + 255) & ~(size_t)255;
        return p;
    };
    short* xb     = (short*)take((size_t)4096 * 1024 * 2);
    short* wqkv_b = (short*)take((size_t)3072 * 1024 * 2);
    short* wo_b   = (short*)take((size_t)1024 * 1024 * 2);
    short* w1_b   = (short*)take((size_t)4096 * 1024 * 2);
    short* w2_b   = (short*)take((size_t)1024 * 4096 * 2);
    short* qkv_b  = (short*)take((size_t)4096 * 3072 * 2);
    short* ctx_b  = (short*)take((size_t)4096 * 1024 * 2);
    float* attn_f = (float*)take((size_t)4096 * 1024 * 4);
    float* h_f    = (float*)take((size_t)4096 * 1024 * 4);
    short* h_b    = (short*)take((size_t)4096 * 1024 * 2);
    short* ff_b   = (short*)take((size_t)4096 * 4096 * 2);
    float* ff2_f  = (float*)take((size_t)4096 * 1024 * 4);

    float* out_f = (float*)d_out;
    float* attnW = (float*)d_out + (size_t)4 * 1024 * 1024;

    hipMemsetAsync(attnW, 0, (size_t)4 * 1024 * 1024 * 4, stream);

    // bf16 conversions
    cvt_kernel<<<4096, 256, 0, stream>>>(x,    xb,     4096 * 1024 / 4);
    cvt_kernel<<<3072, 256, 0, stream>>>(wqkv, wqkv_b, 3072 * 1024 / 4);
    cvt_kernel<<<1024, 256, 0, stream>>>(wo,   wo_b,   1024 * 1024 / 4);
    cvt_kernel<<<4096, 256, 0, stream>>>(w1,   w1_b,   4096 * 1024 / 4);
    cvt_kernel<<<4096, 256, 0, stream>>>(w2,   w2_b,   4096 * 1024 / 4);

    // qkv projection: [4096,1024] x [3072,1024]^T -> bf16
    gemm_bt<false, true><<<dim3(32, 24), 256, 0, stream>>>(
        xb, wqkv_b, bqkv, nullptr, qkv_b, 4096, 3072, 1024);

    // banded attention
    attn_kernel<<<dim3(32, 16, 4), 512, 0, stream>>>(qkv_b, ctx_b, attnW);

    // out projection -> fp32
    gemm_bt<false, false><<<dim3(32, 8), 256, 0, stream>>>(
        ctx_b, wo_b, bo, attn_f, nullptr, 4096, 1024, 1024);

    // h = LN(x + attn_out) -> fp32 + bf16
    ln_kernel<<<4096, 256, 0, stream>>>(x, attn_f, g1, be1, h_f, h_b);

    // FFN1 + ReLU -> bf16
    gemm_bt<true, true><<<dim3(32, 32), 256, 0, stream>>>(
        h_b, w1_b, bb1, nullptr, ff_b, 4096, 4096, 1024);

    // FFN2 -> fp32
    gemm_bt<false, false><<<dim3(32, 8), 256, 0, stream>>>(
        ff_b, w2_b, bb2, ff2_f, nullptr, 4096, 1024, 4096);

    // out = LN(h + ff) -> d_out
    ln_kernel<<<4096, 256, 0, stream>>>(h_f, ff2_f, g2, be2, out_f, nullptr);
}

// Round 2
// 469.384 us; speedup vs baseline: 1.6352x; 1.6352x over previous
//
#include <hip/hip_runtime.h>

// Shapes fixed by setup_inputs(): B=4, L=1024, E=1024, H=16, D=64, W=128
#define BB 4
#define LL 1024
#define EE 1024
#define HH 16
#define DD 64

typedef __attribute__((ext_vector_type(8))) short short8;
typedef __attribute__((ext_vector_type(4))) float floatx4;

__device__ __forceinline__ float bf2f(short s) {
    union { unsigned u; float f; } c;
    c.u = ((unsigned)(unsigned short)s) << 16;
    return c.f;
}
__device__ __forceinline__ short f2bf(float f) {
    union { float f; unsigned u; } c; c.f = f;
    unsigned r = c.u + 0x7fffu + ((c.u >> 16) & 1u);
    return (short)(r >> 16);
}

__device__ __forceinline__ void async_copy16(const void* g, void* l) {
    __builtin_amdgcn_global_load_lds(
        (const __attribute__((address_space(1))) unsigned int*)g,
        (__attribute__((address_space(3))) unsigned int*)l, 16, 0, 0);
}

// ---------------------------------------------------------------- convert
__global__ __launch_bounds__(256) void cvt_kernel(const float* __restrict__ in,
                                                  short* __restrict__ out, int n4) {
    int i = blockIdx.x * 256 + threadIdx.x;
    if (i < n4) {
        float4 v = ((const float4*)in)[i];
        unsigned long long u =
              (unsigned long long)(unsigned short)f2bf(v.x)
            | ((unsigned long long)(unsigned short)f2bf(v.y) << 16)
            | ((unsigned long long)(unsigned short)f2bf(v.z) << 32)
            | ((unsigned long long)(unsigned short)f2bf(v.w) << 48);
        ((unsigned long long*)out)[i] = u;
    }
}

// ---------------------------------------------------------------- GEMM (NT)
// C[m,n] = sum_k A[m,k]*B[n,k] + bias[n]; A:[M,K] bf16, B:[N,K] bf16.
// 128x128 tile, BK=32, 256 thr (4 waves, 2x2 of 64x64), m97 structure.
// WVT: additionally scatter cols >=2048 (the V third of qkv) transposed into
//      VTp[b][h][d][1024] for MFMA B-operand use in attention.
template<bool RELU, bool OUT_BF16, bool WVT>
__global__ __launch_bounds__(256) void gemm_bt(
    const short* __restrict__ A, const short* __restrict__ Bw,
    const float* __restrict__ bias,
    float* __restrict__ Cf, short* __restrict__ Cb, short* __restrict__ VTp,
    int M, int N, int K)
{
    __shared__ short As[4096];
    __shared__ short Bs[4096];
    const int tid  = threadIdx.x;
    const int wave = tid >> 6, lane = tid & 63;
    const int m0 = blockIdx.x * 128, n0 = blockIdx.y * 128;
    const int wm = (wave & 1) * 64, wn = (wave >> 1) * 64;

    floatx4 acc[4][4];
#pragma unroll
    for (int i = 0; i < 4; ++i)
#pragma unroll
        for (int j = 0; j < 4; ++j) acc[i][j] = (floatx4){0.f, 0.f, 0.f, 0.f};

    const int srow = tid >> 2;
    const int skc  = (tid & 3) * 8;
    const short* ga0 = A  + (size_t)(m0 + srow) * K + skc;
    const short* ga1 = A  + (size_t)(m0 + 64 + srow) * K + skc;
    const short* gb0 = Bw + (size_t)(n0 + srow) * K + skc;
    const short* gb1 = Bw + (size_t)(n0 + 64 + srow) * K + skc;
    short* la0 = As + wave * 512;
    short* la1 = As + 2048 + wave * 512;
    short* lb0 = Bs + wave * 512;
    short* lb1 = Bs + 2048 + wave * 512;

    const int fr = lane & 15, fk = (lane >> 4) * 8;
    const int kiters = K >> 5;
    for (int kt = 0; kt < kiters; ++kt) {
        async_copy16(ga0, la0);
        async_copy16(ga1, la1);
        async_copy16(gb0, lb0);
        async_copy16(gb1, lb1);
        ga0 += 32; ga1 += 32; gb0 += 32; gb1 += 32;
        __syncthreads();
        short8 af[4], bfr[4];
#pragma unroll
        for (int i = 0; i < 4; ++i) {
            af[i]  = *(const short8*)&As[(wm + i * 16 + fr) * 32 + fk];
            bfr[i] = *(const short8*)&Bs[(wn + i * 16 + fr) * 32 + fk];
        }
#pragma unroll
        for (int i = 0; i < 4; ++i)
#pragma unroll
            for (int j = 0; j < 4; ++j)
                acc[i][j] = __builtin_amdgcn_mfma_f32_16x16x32_bf16(af[i], bfr[j], acc[i][j], 0, 0, 0);
        __syncthreads();
    }

    const int cc = lane & 15;
    const int rbase = (lane >> 4) * 4;
#pragma unroll
    for (int j = 0; j < 4; ++j) {
        int col = n0 + wn + j * 16 + cc;
        float bv = bias[col];
#pragma unroll
        for (int i = 0; i < 4; ++i) {
            int row = m0 + wm + i * 16 + rbase;
#pragma unroll
            for (int r = 0; r < 4; ++r) {
                float v = acc[i][j][r] + bv;
                if (RELU) v = fmaxf(v, 0.0f);
                if (OUT_BF16) {
                    short b16 = f2bf(v);
                    Cb[(size_t)(row + r) * N + col] = b16;
                    if (WVT && col >= 2048) {
                        int tok = row + r;
                        int hc = (col - 2048) >> 6, dd = (col - 2048) & 63;
                        VTp[((size_t)((tok >> 10) * 16 + hc) * 64 + dd) * 1024 + (tok & 1023)] = b16;
                    }
                } else {
                    Cf[(size_t)(row + r) * N + col] = v;
                }
            }
        }
    }
}

// ---------------------------------------------------------------- LayerNorm
__global__ __launch_bounds__(256) void ln_kernel(
    const float* __restrict__ xa, const float* __restrict__ xb,
    const float* __restrict__ g, const float* __restrict__ beta,
    float* __restrict__ outf, short* __restrict__ outb)
{
    const int row = blockIdx.x;
    const int tid = threadIdx.x;
    float4 va = ((const float4*)(xa + (size_t)row * EE))[tid];
    float4 vb = ((const float4*)(xb + (size_t)row * EE))[tid];
    float v0 = va.x + vb.x, v1 = va.y + vb.y, v2 = va.z + vb.z, v3 = va.w + vb.w;
    float s  = v0 + v1 + v2 + v3;
    float ss = v0 * v0 + v1 * v1 + v2 * v2 + v3 * v3;
#pragma unroll
    for (int o = 1; o < 64; o <<= 1) { s += __shfl_xor(s, o); ss += __shfl_xor(ss, o); }
    __shared__ float red[8];
    if ((tid & 63) == 0) { red[(tid >> 6) * 2] = s; red[(tid >> 6) * 2 + 1] = ss; }
    __syncthreads();
    s  = red[0] + red[2] + red[4] + red[6];
    ss = red[1] + red[3] + red[5] + red[7];
    float mean = s * (1.0f / EE);
    float var  = ss * (1.0f / EE) - mean * mean;
    float rstd = rsqrtf(var + 1e-5f);
    float4 vg = ((const float4*)g)[tid];
    float4 vt = ((const float4*)beta)[tid];
    float o0 = (v0 - mean) * rstd * vg.x + vt.x;
    float o1 = (v1 - mean) * rstd * vg.y + vt.y;
    float o2 = (v2 - mean) * rstd * vg.z + vt.z;
    float o3 = (v3 - mean) * rstd * vg.w + vt.w;
    if (outf) ((float4*)(outf + (size_t)row * EE))[tid] = make_float4(o0, o1, o2, o3);
    if (outb) {
        unsigned long long u =
              (unsigned long long)(unsigned short)f2bf(o0)
            | ((unsigned long long)(unsigned short)f2bf(o1) << 16)
            | ((unsigned long long)(unsigned short)f2bf(o2) << 32)
            | ((unsigned long long)(unsigned short)f2bf(o3) << 48);
        ((unsigned long long*)(outb + (size_t)row * EE))[tid] = u;
    }
}

// ---------------------------------------------------------------- attention (MFMA)
// Block = (i-tile of 32 rows, h, b), 256 thr / 4 waves.
// Window jo in [0,320), global j = i0-128+jo. Row r valid: jo in [r, r+256] & j in [0,1024).
// QK^T: A(Q)/B(K) frags straight from global (16B/lane, L2-resident band).
// S fp32 in LDS (stride 324), wave-parallel row softmax, P bf16 in LDS (stride 322).
// PV: A(P) from LDS, B(V^T) frags from global VT[b][h][d][1024].
// Per-head banded P (bf16) stored to pb[B,H,L,272] for the head-mean reduce.
__global__ __launch_bounds__(256) void attn_mfma(
    const short* __restrict__ qkv,
    const short* __restrict__ vt,
    short* __restrict__ ctxp,
    short* __restrict__ pb)
{
    __shared__ float Sb[32 * 324];   // 41.5 KB
    __shared__ short Pl[32 * 322];   // 20.1 KB
    const int tid = threadIdx.x, wave = tid >> 6, lane = tid & 63;
    const int quad = lane >> 4, mcol = lane & 15;
    const int i0 = blockIdx.x * 32, h = blockIdx.y, b = blockIdx.z;
    const int jb0 = i0 - 128;

    const short* qb = qkv + (size_t)(b * 1024) * 3072 + h * 64;
    const short* kb = qb + 1024;

    // Q A-frags: [m=lane&15][k=quad*8+e]
    short8 aq[2][2];
#pragma unroll
    for (int mt = 0; mt < 2; ++mt)
#pragma unroll
        for (int ks = 0; ks < 2; ++ks)
            aq[mt][ks] = *(const short8*)(qb + (size_t)(i0 + mt * 16 + mcol) * 3072 + ks * 32 + quad * 8);

    floatx4 sacc[2][5];
#pragma unroll
    for (int mt = 0; mt < 2; ++mt)
#pragma unroll
        for (int c = 0; c < 5; ++c) sacc[mt][c] = (floatx4){0.f, 0.f, 0.f, 0.f};

#pragma unroll
    for (int c = 0; c < 5; ++c) {
        int ct = c * 4 + wave;                 // col-tile
        int j = jb0 + ct * 16 + mcol;          // K row (clamped; garbage masked later)
        j = min(max(j, 0), 1023);
        const short* kr = kb + (size_t)j * 3072 + quad * 8;
        short8 b0 = *(const short8*)kr;
        short8 b1 = *(const short8*)(kr + 32);
        sacc[0][c] = __builtin_amdgcn_mfma_f32_16x16x32_bf16(aq[0][0], b0, sacc[0][c], 0, 0, 0);
        sacc[1][c] = __builtin_amdgcn_mfma_f32_16x16x32_bf16(aq[1][0], b0, sacc[1][c], 0, 0, 0);
        sacc[0][c] = __builtin_amdgcn_mfma_f32_16x16x32_bf16(aq[0][1], b1, sacc[0][c], 0, 0, 0);
        sacc[1][c] = __builtin_amdgcn_mfma_f32_16x16x32_bf16(aq[1][1], b1, sacc[1][c], 0, 0, 0);
    }
    // scatter S (C-layout: col=lane&15, row=quad*4+reg) -> <=2-way banks
#pragma unroll
    for (int mt = 0; mt < 2; ++mt)
#pragma unroll
        for (int c = 0; c < 5; ++c) {
            int jo = (c * 4 + wave) * 16 + mcol;
            int rowb = mt * 16 + quad * 4;
#pragma unroll
            for (int r = 0; r < 4; ++r)
                Sb[(rowb + r) * 324 + jo] = sacc[mt][c][r];
        }
    __syncthreads();

    // softmax: wave handles rows wave*8 .. +7; lane covers jo = lane + 64t
    short* pb_base = pb + ((size_t)(b * 16 + h) * 1024 + i0) * 272;
    for (int rr = 0; rr < 8; ++rr) {
        const int r = wave * 8 + rr;
        float sv[5];
#pragma unroll
        for (int t = 0; t < 5; ++t) {
            int jo = lane + t * 64;
            bool val = (jo >= r) && (jo <= r + 256) && ((unsigned)(jb0 + jo) < 1024u);
            sv[t] = val ? Sb[r * 324 + jo] * 0.125f : -1e30f;
        }
        float m = sv[0];
#pragma unroll
        for (int t = 1; t < 5; ++t) m = fmaxf(m, sv[t]);
#pragma unroll
        for (int o = 32; o; o >>= 1) m = fmaxf(m, __shfl_xor(m, o));
        float l = 0.f, p[5];
#pragma unroll
        for (int t = 0; t < 5; ++t) { p[t] = __expf(sv[t] - m); l += p[t]; }
#pragma unroll
        for (int o = 32; o; o >>= 1) l += __shfl_xor(l, o);
        float inv = 1.0f / l;
        short* pbrow = pb_base + (size_t)r * 272;
#pragma unroll
        for (int t = 0; t < 5; ++t) {
            int jo = lane + t * 64;
            short pv = f2bf(p[t] * inv);       // 0 where masked
            Pl[r * 322 + jo] = pv;
            int jr = jo - r;                   // per-row window offset
            if ((unsigned)jr < 272u) pbrow[jr] = pv;
        }
    }
    __syncthreads();

    // PV: wave -> (mt = wave&1, d-tiles dt0, dt0+1)
    const int mt = wave & 1, dt0 = (wave >> 1) * 2;
    floatx4 cacc[2];
    cacc[0] = (floatx4){0.f, 0.f, 0.f, 0.f};
    cacc[1] = (floatx4){0.f, 0.f, 0.f, 0.f};
    const short* vtb = vt + (size_t)((b * 16 + h) * 64) * 1024;
#pragma unroll
    for (int jc = 0; jc < 10; ++jc) {
        short8 ap = *(const short8*)&Pl[(mt * 16 + mcol) * 322 + jc * 32 + quad * 8];
        int jg = jb0 + jc * 32 + quad * 8;     // multiple of 8: never straddles [0,1024)
        if ((unsigned)jg >= 1024u) jg = 0;     // fully-masked frag (P=0) -> safe addr
#pragma unroll
        for (int e = 0; e < 2; ++e) {
            short8 bv = *(const short8*)(vtb + (size_t)((dt0 + e) * 16 + mcol) * 1024 + jg);
            cacc[e] = __builtin_amdgcn_mfma_f32_16x16x32_bf16(ap, bv, cacc[e], 0, 0, 0);
        }
    }
#pragma unroll
    for (int e = 0; e < 2; ++e) {
        int col = h * 64 + (dt0 + e) * 16 + mcol;
#pragma unroll
        for (int r = 0; r < 4; ++r) {
            int row = i0 + mt * 16 + quad * 4 + r;
            ctxp[(size_t)(b * 1024 + row) * 1024 + col] = f2bf(cacc[e][r]);
        }
    }
}

// ---------------------------------------------------------------- head-mean reduce
// attnW[b][i][j] = mean_h P[b][h][i][j-i+128]; writes full rows (zeros outside band).
__global__ __launch_bounds__(256) void pb_reduce(const short* __restrict__ pb,
                                                 float* __restrict__ aw)
{
    const int i = blockIdx.x & 1023, b = blockIdx.x >> 10;
    const short* base = pb + ((size_t)(b * 16) * 1024 + i) * 272;
    float* row = aw + ((size_t)(b * 1024) + i) * 1024;
    for (int j = threadIdx.x; j < 1024; j += 256) {
        int jr = j - i + 128;
        float s = 0.f;
        if ((unsigned)jr < 272u) {
#pragma unroll
            for (int hh = 0; hh < 16; ++hh)
                s += bf2f(base[(size_t)hh * 1024 * 272 + jr]);
            s *= (1.0f / 16.0f);
        }
        row[j] = s;
    }
}

// ---------------------------------------------------------------- launch
extern "C" void kernel_launch(void* const* d_in, const int* in_sizes, int n_in,
                              void* d_out, int out_size, void* d_ws, size_t ws_size,
                              hipStream_t stream) {
    const float* x    = (const float*)d_in[0];
    const float* wqkv = (const float*)d_in[1];
    const float* bqkv = (const float*)d_in[2];
    const float* wo   = (const float*)d_in[3];
    const float* bo   = (const float*)d_in[4];
    const float* g1   = (const float*)d_in[5];
    const float* be1  = (const float*)d_in[6];
    const float* w1   = (const float*)d_in[7];
    const float* bb1  = (const float*)d_in[8];
    const float* w2   = (const float*)d_in[9];
    const float* bb2  = (const float*)d_in[10];
    const float* g2   = (const float*)d_in[11];
    const float* be2  = (const float*)d_in[12];

    char* ws = (char*)d_ws;
    size_t off = 0;
    auto take = [&](size_t bytes) {
        void* p = ws + off;
        off += (bytes + 255) & ~(size_t)255;
        return p;
    };
    short* xb     = (short*)take((size_t)4096 * 1024 * 2);
    short* wqkv_b = (short*)take((size_t)3072 * 1024 * 2);
    short* wo_b   = (short*)take((size_t)1024 * 1024 * 2);
    short* w1_b   = (short*)take((size_t)4096 * 1024 * 2);
    short* w2_b   = (short*)take((size_t)1024 * 4096 * 2);
    short* qkv_b  = (short*)take((size_t)4096 * 3072 * 2);
    short* ctx_b  = (short*)take((size_t)4096 * 1024 * 2);
    float* attn_f = (float*)take((size_t)4096 * 1024 * 4);
    float* h_f    = (float*)take((size_t)4096 * 1024 * 4);
    short* h_b    = (short*)take((size_t)4096 * 1024 * 2);
    // ff_b aliases pb (lifetimes disjoint: pb done at pb_reduce, ff_b starts at FFN1)
    short* pb_ws  = (short*)take((size_t)4 * 16 * 1024 * 272 * 2);   // 35.7 MB
    short* ff_b   = pb_ws;                                           // 33.6 MB <= region
    // ff2_f aliases vt (vt done after attn, ff2_f starts at FFN2)
    float* ff2_f  = (float*)take((size_t)4096 * 1024 * 4);           // 16.8 MB
    short* vt_ws  = (short*)ff2_f;                                   // 8.4 MB <= region

    float* out_f = (float*)d_out;
    float* attnW = (float*)d_out + (size_t)4 * 1024 * 1024;

    // bf16 conversions
    cvt_kernel<<<4096, 256, 0, stream>>>(x,    xb,     4096 * 1024 / 4);
    cvt_kernel<<<3072, 256, 0, stream>>>(wqkv, wqkv_b, 3072 * 1024 / 4);
    cvt_kernel<<<1024, 256, 0, stream>>>(wo,   wo_b,   1024 * 1024 / 4);
    cvt_kernel<<<4096, 256, 0, stream>>>(w1,   w1_b,   4096 * 1024 / 4);
    cvt_kernel<<<4096, 256, 0, stream>>>(w2,   w2_b,   4096 * 1024 / 4);

    // qkv projection (also writes V transposed into vt_ws)
    gemm_bt<false, true, true><<<dim3(32, 24), 256, 0, stream>>>(
        xb, wqkv_b, bqkv, nullptr, qkv_b, vt_ws, 4096, 3072, 1024);

    // banded attention (MFMA)
    attn_mfma<<<dim3(32, 16, 4), 256, 0, stream>>>(qkv_b, vt_ws, ctx_b, pb_ws);

    // head-mean attention weights
    pb_reduce<<<4096, 256, 0, stream>>>(pb_ws, attnW);

    // out projection -> fp32
    gemm_bt<false, false, false><<<dim3(32, 8), 256, 0, stream>>>(
        ctx_b, wo_b, bo, attn_f, nullptr, nullptr, 4096, 1024, 1024);

    // h = LN(x + attn_out) -> fp32 + bf16
    ln_kernel<<<4096, 256, 0, stream>>>(x, attn_f, g1, be1, h_f, h_b);

    // FFN1 + ReLU -> bf16
    gemm_bt<true, true, false><<<dim3(32, 32), 256, 0, stream>>>(
        h_b, w1_b, bb1, nullptr, ff_b, nullptr, 4096, 4096, 1024);

    // FFN2 -> fp32
    gemm_bt<false, false, false><<<dim3(32, 8), 256, 0, stream>>>(
        ff_b, w2_b, bb2, ff2_f, nullptr, nullptr, 4096, 1024, 4096);

    // out = LN(h + ff) -> d_out
    ln_kernel<<<4096, 256, 0, stream>>>(h_f, ff2_f, g2, be2, out_f, nullptr);
}

// Round 3
// 434.707 us; speedup vs baseline: 1.7657x; 1.0798x over previous
//
#include <hip/hip_runtime.h>

// Shapes fixed by setup_inputs(): B=4, L=1024, E=1024, H=16, D=64, W=128
#define BB 4
#define LL 1024
#define EE 1024
#define HH 16
#define DD 64

typedef __attribute__((ext_vector_type(8))) short short8;
typedef __attribute__((ext_vector_type(4))) float floatx4;

#define PSTR ((size_t)4096 * 1024)   // partial-buffer stride (elements)

__device__ __forceinline__ float bf2f(short s) {
    union { unsigned u; float f; } c;
    c.u = ((unsigned)(unsigned short)s) << 16;
    return c.f;
}
__device__ __forceinline__ short f2bf(float f) {
    union { float f; unsigned u; } c; c.f = f;
    unsigned r = c.u + 0x7fffu + ((c.u >> 16) & 1u);
    return (short)(r >> 16);
}

__device__ __forceinline__ void async_copy16(const void* g, void* l) {
    __builtin_amdgcn_global_load_lds(
        (const __attribute__((address_space(1))) unsigned int*)g,
        (__attribute__((address_space(3))) unsigned int*)l, 16, 0, 0);
}

// ---------------------------------------------------------------- convert (all 5 tensors, one launch)
__global__ __launch_bounds__(256) void cvt5(
    const float* __restrict__ x, const float* __restrict__ wqkv,
    const float* __restrict__ wo, const float* __restrict__ w1,
    const float* __restrict__ w2,
    short* __restrict__ xb, short* __restrict__ wqkvb, short* __restrict__ wob,
    short* __restrict__ w1b, short* __restrict__ w2b)
{
    int bi = blockIdx.x;
    const float* in; short* out; int base;
    if      (bi <  4096) { in = x;    out = xb;    base = 0;     }
    else if (bi <  7168) { in = wqkv; out = wqkvb; base = 4096;  }
    else if (bi <  8192) { in = wo;   out = wob;   base = 7168;  }
    else if (bi < 12288) { in = w1;   out = w1b;   base = 8192;  }
    else                 { in = w2;   out = w2b;   base = 12288; }
    int i = (bi - base) * 256 + threadIdx.x;
    float4 v = ((const float4*)in)[i];
    unsigned long long u =
          (unsigned long long)(unsigned short)f2bf(v.x)
        | ((unsigned long long)(unsigned short)f2bf(v.y) << 16)
        | ((unsigned long long)(unsigned short)f2bf(v.z) << 32)
        | ((unsigned long long)(unsigned short)f2bf(v.w) << 48);
    ((unsigned long long*)out)[i] = u;
}

// ---------------------------------------------------------------- GEMM (NT)
// C[m,n] = sum_k A[m,k]*B[n,k] + bias[n]; 128x128 tile, BK=32, 256 thr.
template<bool RELU, bool WVT>
__global__ __launch_bounds__(256) void gemm_bt(
    const short* __restrict__ A, const short* __restrict__ Bw,
    const float* __restrict__ bias,
    short* __restrict__ Cb, short* __restrict__ VTp,
    int M, int N, int K)
{
    __shared__ short As[4096];
    __shared__ short Bs[4096];
    const int tid  = threadIdx.x;
    const int wave = tid >> 6, lane = tid & 63;
    const int m0 = blockIdx.x * 128, n0 = blockIdx.y * 128;
    const int wm = (wave & 1) * 64, wn = (wave >> 1) * 64;

    floatx4 acc[4][4];
#pragma unroll
    for (int i = 0; i < 4; ++i)
#pragma unroll
        for (int j = 0; j < 4; ++j) acc[i][j] = (floatx4){0.f, 0.f, 0.f, 0.f};

    const int srow = tid >> 2;
    const int skc  = (tid & 3) * 8;
    const short* ga0 = A  + (size_t)(m0 + srow) * K + skc;
    const short* ga1 = A  + (size_t)(m0 + 64 + srow) * K + skc;
    const short* gb0 = Bw + (size_t)(n0 + srow) * K + skc;
    const short* gb1 = Bw + (size_t)(n0 + 64 + srow) * K + skc;
    short* la0 = As + wave * 512;
    short* la1 = As + 2048 + wave * 512;
    short* lb0 = Bs + wave * 512;
    short* lb1 = Bs + 2048 + wave * 512;

    const int fr = lane & 15, fk = (lane >> 4) * 8;
    const int kiters = K >> 5;
    for (int kt = 0; kt < kiters; ++kt) {
        async_copy16(ga0, la0);
        async_copy16(ga1, la1);
        async_copy16(gb0, lb0);
        async_copy16(gb1, lb1);
        ga0 += 32; ga1 += 32; gb0 += 32; gb1 += 32;
        __syncthreads();
        short8 af[4], bfr[4];
#pragma unroll
        for (int i = 0; i < 4; ++i) {
            af[i]  = *(const short8*)&As[(wm + i * 16 + fr) * 32 + fk];
            bfr[i] = *(const short8*)&Bs[(wn + i * 16 + fr) * 32 + fk];
        }
#pragma unroll
        for (int i = 0; i < 4; ++i)
#pragma unroll
            for (int j = 0; j < 4; ++j)
                acc[i][j] = __builtin_amdgcn_mfma_f32_16x16x32_bf16(af[i], bfr[j], acc[i][j], 0, 0, 0);
        __syncthreads();
    }

    const int cc = lane & 15;
    const int rbase = (lane >> 4) * 4;
#pragma unroll
    for (int j = 0; j < 4; ++j) {
        int col = n0 + wn + j * 16 + cc;
        float bv = bias[col];
#pragma unroll
        for (int i = 0; i < 4; ++i) {
            int row = m0 + wm + i * 16 + rbase;
#pragma unroll
            for (int r = 0; r < 4; ++r) {
                float v = acc[i][j][r] + bv;
                if (RELU) v = fmaxf(v, 0.0f);
                short b16 = f2bf(v);
                Cb[(size_t)(row + r) * N + col] = b16;
                if (WVT && col >= 2048) {
                    int tok = row + r;
                    int hc = (col - 2048) >> 6, dd = (col - 2048) & 63;
                    VTp[((size_t)((tok >> 10) * 16 + hc) * 64 + dd) * 1024 + (tok & 1023)] = b16;
                }
            }
        }
    }
}

// ---------------------------------------------------------------- GEMM split-K
// Partial C (no bias) -> Cf + z*PSTR; grid.z = #splits, each covers Ksp of K.
__global__ __launch_bounds__(256) void gemm_sk(
    const short* __restrict__ A, const short* __restrict__ Bw,
    float* __restrict__ Cf, int M, int N, int K, int Ksp)
{
    __shared__ short As[4096];
    __shared__ short Bs[4096];
    const int tid  = threadIdx.x;
    const int wave = tid >> 6, lane = tid & 63;
    const int m0 = blockIdx.x * 128, n0 = blockIdx.y * 128;
    const int z  = blockIdx.z;
    const int wm = (wave & 1) * 64, wn = (wave >> 1) * 64;

    floatx4 acc[4][4];
#pragma unroll
    for (int i = 0; i < 4; ++i)
#pragma unroll
        for (int j = 0; j < 4; ++j) acc[i][j] = (floatx4){0.f, 0.f, 0.f, 0.f};

    const int srow = tid >> 2;
    const int skc  = z * Ksp + (tid & 3) * 8;
    const short* ga0 = A  + (size_t)(m0 + srow) * K + skc;
    const short* ga1 = A  + (size_t)(m0 + 64 + srow) * K + skc;
    const short* gb0 = Bw + (size_t)(n0 + srow) * K + skc;
    const short* gb1 = Bw + (size_t)(n0 + 64 + srow) * K + skc;
    short* la0 = As + wave * 512;
    short* la1 = As + 2048 + wave * 512;
    short* lb0 = Bs + wave * 512;
    short* lb1 = Bs + 2048 + wave * 512;

    const int fr = lane & 15, fk = (lane >> 4) * 8;
    const int kiters = Ksp >> 5;
    for (int kt = 0; kt < kiters; ++kt) {
        async_copy16(ga0, la0);
        async_copy16(ga1, la1);
        async_copy16(gb0, lb0);
        async_copy16(gb1, lb1);
        ga0 += 32; ga1 += 32; gb0 += 32; gb1 += 32;
        __syncthreads();
        short8 af[4], bfr[4];
#pragma unroll
        for (int i = 0; i < 4; ++i) {
            af[i]  = *(const short8*)&As[(wm + i * 16 + fr) * 32 + fk];
            bfr[i] = *(const short8*)&Bs[(wn + i * 16 + fr) * 32 + fk];
        }
#pragma unroll
        for (int i = 0; i < 4; ++i)
#pragma unroll
            for (int j = 0; j < 4; ++j)
                acc[i][j] = __builtin_amdgcn_mfma_f32_16x16x32_bf16(af[i], bfr[j], acc[i][j], 0, 0, 0);
        __syncthreads();
    }

    float* Co = Cf + (size_t)z * PSTR;
    const int cc = lane & 15;
    const int rbase = (lane >> 4) * 4;
#pragma unroll
    for (int j = 0; j < 4; ++j) {
        int col = n0 + wn + j * 16 + cc;
#pragma unroll
        for (int i = 0; i < 4; ++i) {
            int row = m0 + wm + i * 16 + rbase;
#pragma unroll
            for (int r = 0; r < 4; ++r)
                Co[(size_t)(row + r) * N + col] = acc[i][j][r];
        }
    }
}

// ---------------------------------------------------------------- LayerNorm
// v = xa + sum_p parts[p] + bias; out = LN(v)*g + beta.
__global__ __launch_bounds__(256) void ln_kernel(
    const float* __restrict__ xa, const float* __restrict__ parts, int nparts,
    const float* __restrict__ bias,
    const float* __restrict__ g, const float* __restrict__ beta,
    float* __restrict__ outf, short* __restrict__ outb)
{
    const int row = blockIdx.x;
    const int tid = threadIdx.x;
    float4 va = ((const float4*)(xa + (size_t)row * EE))[tid];
    float4 vb = ((const float4*)bias)[tid];
    float v0 = va.x + vb.x, v1 = va.y + vb.y, v2 = va.z + vb.z, v3 = va.w + vb.w;
#pragma unroll 4
    for (int p = 0; p < nparts; ++p) {
        float4 vp = ((const float4*)(parts + p * PSTR + (size_t)row * EE))[tid];
        v0 += vp.x; v1 += vp.y; v2 += vp.z; v3 += vp.w;
    }
    float s  = v0 + v1 + v2 + v3;
    float ss = v0 * v0 + v1 * v1 + v2 * v2 + v3 * v3;
#pragma unroll
    for (int o = 1; o < 64; o <<= 1) { s += __shfl_xor(s, o); ss += __shfl_xor(ss, o); }
    __shared__ float red[8];
    if ((tid & 63) == 0) { red[(tid >> 6) * 2] = s; red[(tid >> 6) * 2 + 1] = ss; }
    __syncthreads();
    s  = red[0] + red[2] + red[4] + red[6];
    ss = red[1] + red[3] + red[5] + red[7];
    float mean = s * (1.0f / EE);
    float var  = ss * (1.0f / EE) - mean * mean;
    float rstd = rsqrtf(var + 1e-5f);
    float4 vg = ((const float4*)g)[tid];
    float4 vt = ((const float4*)beta)[tid];
    float o0 = (v0 - mean) * rstd * vg.x + vt.x;
    float o1 = (v1 - mean) * rstd * vg.y + vt.y;
    float o2 = (v2 - mean) * rstd * vg.z + vt.z;
    float o3 = (v3 - mean) * rstd * vg.w + vt.w;
    if (outf) ((float4*)(outf + (size_t)row * EE))[tid] = make_float4(o0, o1, o2, o3);
    if (outb) {
        unsigned long long u =
              (unsigned long long)(unsigned short)f2bf(o0)
            | ((unsigned long long)(unsigned short)f2bf(o1) << 16)
            | ((unsigned long long)(unsigned short)f2bf(o2) << 32)
            | ((unsigned long long)(unsigned short)f2bf(o3) << 48);
        ((unsigned long long*)(outb + (size_t)row * EE))[tid] = u;
    }
}

// ---------------------------------------------------------------- attention (MFMA)
// Block = (i-tile of 32 rows, h, b), 256 thr / 4 waves.
__global__ __launch_bounds__(256) void attn_mfma(
    const short* __restrict__ qkv,
    const short* __restrict__ vt,
    short* __restrict__ ctxp,
    short* __restrict__ pb)     // [b][i][h][272] bf16
{
    __shared__ float Sb[32 * 324];   // 41.5 KB
    __shared__ short Pl[32 * 322];   // 20.1 KB
    const int tid = threadIdx.x, wave = tid >> 6, lane = tid & 63;
    const int quad = lane >> 4, mcol = lane & 15;
    const int i0 = blockIdx.x * 32, h = blockIdx.y, b = blockIdx.z;
    const int jb0 = i0 - 128;

    const short* qb = qkv + (size_t)(b * 1024) * 3072 + h * 64;
    const short* kb = qb + 1024;

    short8 aq[2][2];
#pragma unroll
    for (int mt = 0; mt < 2; ++mt)
#pragma unroll
        for (int ks = 0; ks < 2; ++ks)
            aq[mt][ks] = *(const short8*)(qb + (size_t)(i0 + mt * 16 + mcol) * 3072 + ks * 32 + quad * 8);

    floatx4 sacc[2][5];
#pragma unroll
    for (int mt = 0; mt < 2; ++mt)
#pragma unroll
        for (int c = 0; c < 5; ++c) sacc[mt][c] = (floatx4){0.f, 0.f, 0.f, 0.f};

#pragma unroll
    for (int c = 0; c < 5; ++c) {
        int ct = c * 4 + wave;
        int j = jb0 + ct * 16 + mcol;
        j = min(max(j, 0), 1023);
        const short* kr = kb + (size_t)j * 3072 + quad * 8;
        short8 b0 = *(const short8*)kr;
        short8 b1 = *(const short8*)(kr + 32);
        sacc[0][c] = __builtin_amdgcn_mfma_f32_16x16x32_bf16(aq[0][0], b0, sacc[0][c], 0, 0, 0);
        sacc[1][c] = __builtin_amdgcn_mfma_f32_16x16x32_bf16(aq[1][0], b0, sacc[1][c], 0, 0, 0);
        sacc[0][c] = __builtin_amdgcn_mfma_f32_16x16x32_bf16(aq[0][1], b1, sacc[0][c], 0, 0, 0);
        sacc[1][c] = __builtin_amdgcn_mfma_f32_16x16x32_bf16(aq[1][1], b1, sacc[1][c], 0, 0, 0);
    }
#pragma unroll
    for (int mt = 0; mt < 2; ++mt)
#pragma unroll
        for (int c = 0; c < 5; ++c) {
            int jo = (c * 4 + wave) * 16 + mcol;
            int rowb = mt * 16 + quad * 4;
#pragma unroll
            for (int r = 0; r < 4; ++r)
                Sb[(rowb + r) * 324 + jo] = sacc[mt][c][r];
        }
    __syncthreads();

    for (int rr = 0; rr < 8; ++rr) {
        const int r = wave * 8 + rr;
        float sv[5];
#pragma unroll
        for (int t = 0; t < 5; ++t) {
            int jo = lane + t * 64;
            bool val = (jo >= r) && (jo <= r + 256) && ((unsigned)(jb0 + jo) < 1024u);
            sv[t] = val ? Sb[r * 324 + jo] * 0.125f : -1e30f;
        }
        float m = sv[0];
#pragma unroll
        for (int t = 1; t < 5; ++t) m = fmaxf(m, sv[t]);
#pragma unroll
        for (int o = 32; o; o >>= 1) m = fmaxf(m, __shfl_xor(m, o));
        float l = 0.f, p[5];
#pragma unroll
        for (int t = 0; t < 5; ++t) { p[t] = __expf(sv[t] - m); l += p[t]; }
#pragma unroll
        for (int o = 32; o; o >>= 1) l += __shfl_xor(l, o);
        float inv = 1.0f / l;
        short* pbrow = pb + ((size_t)(b * 1024 + i0 + r) * 16 + h) * 272;
#pragma unroll
        for (int t = 0; t < 5; ++t) {
            int jo = lane + t * 64;
            short pv = f2bf(p[t] * inv);
            Pl[r * 322 + jo] = pv;
            int jr = jo - r;
            if ((unsigned)jr < 272u) pbrow[jr] = pv;
        }
    }
    __syncthreads();

    const int mt = wave & 1, dt0 = (wave >> 1) * 2;
    floatx4 cacc[2];
    cacc[0] = (floatx4){0.f, 0.f, 0.f, 0.f};
    cacc[1] = (floatx4){0.f, 0.f, 0.f, 0.f};
    const short* vtb = vt + (size_t)((b * 16 + h) * 64) * 1024;
#pragma unroll
    for (int jc = 0; jc < 10; ++jc) {
        short8 ap = *(const short8*)&Pl[(mt * 16 + mcol) * 322 + jc * 32 + quad * 8];
        int jg = jb0 + jc * 32 + quad * 8;
        if ((unsigned)jg >= 1024u) jg = 0;
#pragma unroll
        for (int e = 0; e < 2; ++e) {
            short8 bv = *(const short8*)(vtb + (size_t)((dt0 + e) * 16 + mcol) * 1024 + jg);
            cacc[e] = __builtin_amdgcn_mfma_f32_16x16x32_bf16(ap, bv, cacc[e], 0, 0, 0);
        }
    }
#pragma unroll
    for (int e = 0; e < 2; ++e) {
        int col = h * 64 + (dt0 + e) * 16 + mcol;
#pragma unroll
        for (int r = 0; r < 4; ++r) {
            int row = i0 + mt * 16 + quad * 4 + r;
            ctxp[(size_t)(b * 1024 + row) * 1024 + col] = f2bf(cacc[e][r]);
        }
    }
}

// ---------------------------------------------------------------- head-mean reduce
__global__ __launch_bounds__(256) void pb_reduce(const short* __restrict__ pb,
                                                 float* __restrict__ aw)
{
    const int i = blockIdx.x & 1023, b = blockIdx.x >> 10;
    __shared__ short P[16 * 272];    // 8704 B, contiguous in pb
    const unsigned* src = (const unsigned*)(pb + (size_t)(b * 1024 + i) * 16 * 272);
    for (int t = threadIdx.x; t < 16 * 272 / 2; t += 256)
        ((unsigned*)P)[t] = src[t];
    __syncthreads();
    float* row = aw + ((size_t)(b * 1024) + i) * 1024;
    for (int j = threadIdx.x; j < 1024; j += 256) {
        int jr = j - i + 128;
        float s = 0.f;
        if ((unsigned)jr < 272u) {
#pragma unroll
            for (int hh = 0; hh < 16; ++hh)
                s += bf2f(P[hh * 272 + jr]);
            s *= (1.0f / 16.0f);
        }
        row[j] = s;
    }
}

// ---------------------------------------------------------------- launch
extern "C" void kernel_launch(void* const* d_in, const int* in_sizes, int n_in,
                              void* d_out, int out_size, void* d_ws, size_t ws_size,
                              hipStream_t stream) {
    const float* x    = (const float*)d_in[0];
    const float* wqkv = (const float*)d_in[1];
    const float* bqkv = (const float*)d_in[2];
    const float* wo   = (const float*)d_in[3];
    const float* bo   = (const float*)d_in[4];
    const float* g1   = (const float*)d_in[5];
    const float* be1  = (const float*)d_in[6];
    const float* w1   = (const float*)d_in[7];
    const float* bb1  = (const float*)d_in[8];
    const float* w2   = (const float*)d_in[9];
    const float* bb2  = (const float*)d_in[10];
    const float* g2   = (const float*)d_in[11];
    const float* be2  = (const float*)d_in[12];

    char* ws = (char*)d_ws;
    size_t off = 0;
    auto take = [&](size_t bytes) {
        void* p = ws + off;
        off += (bytes + 255) & ~(size_t)255;
        return p;
    };
    short* xb     = (short*)take((size_t)4096 * 1024 * 2);
    short* wqkv_b = (short*)take((size_t)3072 * 1024 * 2);
    short* wo_b   = (short*)take((size_t)1024 * 1024 * 2);
    short* w1_b   = (short*)take((size_t)4096 * 1024 * 2);
    short* w2_b   = (short*)take((size_t)1024 * 4096 * 2);
    // qkv_b(25.2) + ctx_b(8.4) + attn_p(33.6) = 67.1 MB, re-used as the 4
    // FFN2 split-K partials (exactly 67.1 MB; lifetimes disjoint).
    short* qkv_b  = (short*)take((size_t)4096 * 3072 * 2);
    short* ctx_b  = (short*)take((size_t)4096 * 1024 * 2);
    float* attn_p = (float*)take((size_t)2 * 4096 * 1024 * 4);   // out-proj partials x2
    float* ff2_p  = (float*)qkv_b;                               // FFN2 partials x4
    float* h_f    = (float*)take((size_t)4096 * 1024 * 4);
    short* vt_ws  = (short*)h_f;                                 // vt dead before ln1 writes h_f
    short* h_b    = (short*)take((size_t)4096 * 1024 * 2);
    short* pb_ws  = (short*)take((size_t)4 * 1024 * 16 * 272 * 2);  // 35.7 MB
    short* ff_b   = pb_ws;                                       // FFN1 out aliases pb (33.6 <= 35.7)

    float* out_f = (float*)d_out;
    float* attnW = (float*)d_out + (size_t)4 * 1024 * 1024;

    // bf16 conversions (single launch)
    cvt5<<<16384, 256, 0, stream>>>(x, wqkv, wo, w1, w2, xb, wqkv_b, wo_b, w1_b, w2_b);

    // qkv projection (also writes V transposed into vt_ws)
    gemm_bt<false, true><<<dim3(32, 24), 256, 0, stream>>>(
        xb, wqkv_b, bqkv, qkv_b, vt_ws, 4096, 3072, 1024);

    // banded attention (MFMA)
    attn_mfma<<<dim3(32, 16, 4), 256, 0, stream>>>(qkv_b, vt_ws, ctx_b, pb_ws);

    // head-mean attention weights
    pb_reduce<<<4096, 256, 0, stream>>>(pb_ws, attnW);

    // out projection, split-K=2 -> fp32 partials
    gemm_sk<<<dim3(32, 8, 2), 256, 0, stream>>>(
        ctx_b, wo_b, attn_p, 4096, 1024, 1024, 512);

    // h = LN(x + p0 + p1 + bo)
    ln_kernel<<<4096, 256, 0, stream>>>(x, attn_p, 2, bo, g1, be1, h_f, h_b);

    // FFN1 + ReLU -> bf16
    gemm_bt<true, false><<<dim3(32, 32), 256, 0, stream>>>(
        h_b, w1_b, bb1, ff_b, nullptr, 4096, 4096, 1024);

    // FFN2, split-K=4 -> fp32 partials
    gemm_sk<<<dim3(32, 8, 4), 256, 0, stream>>>(
        ff_b, w2_b, ff2_p, 4096, 1024, 4096, 1024);

    // out = LN(h + p0..p3 + bb2)
    ln_kernel<<<4096, 256, 0, stream>>>(h_f, ff2_p, 4, bb2, g2, be2, out_f, nullptr);
}

// Round 4
// 406.059 us; speedup vs baseline: 1.8902x; 1.0706x over previous
//
#include <hip/hip_runtime.h>

// Shapes fixed by setup_inputs(): B=4, L=1024, E=1024, H=16, D=64, W=128
#define BB 4
#define LL 1024
#define EE 1024
#define HH 16
#define DD 64

typedef __attribute__((ext_vector_type(8))) short short8;
typedef __attribute__((ext_vector_type(4))) float floatx4;

#define PSTR ((size_t)4096 * 1024)   // split-K partial stride (elements, bf16)

__device__ __forceinline__ float bf2f(short s) {
    union { unsigned u; float f; } c;
    c.u = ((unsigned)(unsigned short)s) << 16;
    return c.f;
}
__device__ __forceinline__ short f2bf(float f) {
    union { float f; unsigned u; } c; c.f = f;
    unsigned r = c.u + 0x7fffu + ((c.u >> 16) & 1u);
    return (short)(r >> 16);
}

__device__ __forceinline__ void async_copy16(const void* g, void* l) {
    __builtin_amdgcn_global_load_lds(
        (const __attribute__((address_space(1))) unsigned int*)g,
        (__attribute__((address_space(3))) unsigned int*)l, 16, 0, 0);
}

// ---------------------------------------------------------------- convert (all 5 tensors, one launch)
__global__ __launch_bounds__(256) void cvt5(
    const float* __restrict__ x, const float* __restrict__ wqkv,
    const float* __restrict__ wo, const float* __restrict__ w1,
    const float* __restrict__ w2,
    short* __restrict__ xb, short* __restrict__ wqkvb, short* __restrict__ wob,
    short* __restrict__ w1b, short* __restrict__ w2b)
{
    int bi = blockIdx.x;
    const float* in; short* out; int base;
    if      (bi <  4096) { in = x;    out = xb;    base = 0;     }
    else if (bi <  7168) { in = wqkv; out = wqkvb; base = 4096;  }
    else if (bi <  8192) { in = wo;   out = wob;   base = 7168;  }
    else if (bi < 12288) { in = w1;   out = w1b;   base = 8192;  }
    else                 { in = w2;   out = w2b;   base = 12288; }
    int i = (bi - base) * 256 + threadIdx.x;
    float4 v = ((const float4*)in)[i];
    unsigned long long u =
          (unsigned long long)(unsigned short)f2bf(v.x)
        | ((unsigned long long)(unsigned short)f2bf(v.y) << 16)
        | ((unsigned long long)(unsigned short)f2bf(v.z) << 32)
        | ((unsigned long long)(unsigned short)f2bf(v.w) << 48);
    ((unsigned long long*)out)[i] = u;
}

// ---------------------------------------------------------------- GEMM (NT)
// C[m,n] = sum_k A[m,k]*B[n,k] (+bias); 128x128 tile, BK=64, 256 thr.
// Output always bf16. SK: blockIdx.z selects K-split, out += z*PSTR, no bias.
// WVT: scatter cols>=2048 transposed into VTp[b][h][d][1024].
// Epilogue: acc -> bf16 LDS tile (stride 136) -> 16B coalesced stores.
template<bool RELU, bool WVT, bool SK>
__global__ __launch_bounds__(256) void gemm_bt(
    const short* __restrict__ A, const short* __restrict__ Bw,
    const float* __restrict__ bias,
    short* __restrict__ Cb, short* __restrict__ VTp,
    int M, int N, int K, int Ksp)
{
    __shared__ union U {
        struct { short As[128 * 64]; short Bs[128 * 64]; } s;
        short Cs[128 * 136];
    } u;   // 34,816 B -> 4 blocks/CU (LDS-limited)
    const int tid  = threadIdx.x;
    const int wave = tid >> 6, lane = tid & 63;
    const int m0 = blockIdx.x * 128, n0 = blockIdx.y * 128;
    const int wm = (wave & 1) * 64, wn = (wave >> 1) * 64;
    const int kbase = SK ? blockIdx.z * Ksp : 0;

    floatx4 acc[4][4];
#pragma unroll
    for (int i = 0; i < 4; ++i)
#pragma unroll
        for (int j = 0; j < 4; ++j) acc[i][j] = (floatx4){0.f, 0.f, 0.f, 0.f};

    // staging: wave w covers rows {s*32 + w*8 + (lane>>3)}, cols (lane&7)*8
    const int srow = wave * 8 + (lane >> 3);
    const int scol = (lane & 7) * 8;
    const short* gA = A  + (size_t)(m0 + srow) * K + kbase + scol;
    const short* gB = Bw + (size_t)(n0 + srow) * K + kbase + scol;
    short* lA = u.s.As + wave * 512;   // + s*2048; DMA adds lane*16B
    short* lB = u.s.Bs + wave * 512;

    const int fr = lane & 15, fk = (lane >> 4) * 8;
    const int kiters = (SK ? Ksp : K) >> 6;
    for (int kt = 0; kt < kiters; ++kt) {
#pragma unroll
        for (int s = 0; s < 4; ++s) {
            async_copy16(gA + (size_t)s * 32 * K, lA + s * 2048);
            async_copy16(gB + (size_t)s * 32 * K, lB + s * 2048);
        }
        gA += 64; gB += 64;
        __syncthreads();
#pragma unroll
        for (int ks = 0; ks < 2; ++ks) {
            short8 af[4], bf[4];
#pragma unroll
            for (int i = 0; i < 4; ++i) {
                af[i] = *(const short8*)&u.s.As[(wm + i * 16 + fr) * 64 + ks * 32 + fk];
                bf[i] = *(const short8*)&u.s.Bs[(wn + i * 16 + fr) * 64 + ks * 32 + fk];
            }
#pragma unroll
            for (int i = 0; i < 4; ++i)
#pragma unroll
                for (int j = 0; j < 4; ++j)
                    acc[i][j] = __builtin_amdgcn_mfma_f32_16x16x32_bf16(af[i], bf[j], acc[i][j], 0, 0, 0);
        }
        __syncthreads();
    }

    // ---- epilogue: C-layout regs -> bf16 LDS tile (stride 136) ----
    const int cc = lane & 15;
    const int rb = (lane >> 4) * 4;
#pragma unroll
    for (int j = 0; j < 4; ++j) {
        int col = wn + j * 16 + cc;
        float bv = SK ? 0.0f : bias[n0 + col];
#pragma unroll
        for (int i = 0; i < 4; ++i) {
            int row = wm + i * 16 + rb;
#pragma unroll
            for (int r = 0; r < 4; ++r) {
                float v = acc[i][j][r] + bv;
                if (RELU) v = fmaxf(v, 0.0f);
                u.Cs[(row + r) * 136 + col] = f2bf(v);
            }
        }
    }
    __syncthreads();
    // ---- coalesced 16B stores ----
    short* Co = Cb + (SK ? (size_t)blockIdx.z * PSTR : 0);
    const int trow = tid >> 4, tcol = (tid & 15) * 8;
#pragma unroll
    for (int p = 0; p < 8; ++p) {
        int row = p * 16 + trow;
        short8 vv = *(const short8*)&u.Cs[row * 136 + tcol];
        *(short8*)&Co[(size_t)(m0 + row) * N + n0 + tcol] = vv;
        if (WVT) {
            int gc0 = n0 + tcol;
            if (gc0 >= 2048) {
                int tok = m0 + row;
                int hc = (gc0 - 2048) >> 6, d0 = (gc0 - 2048) & 63;
                short* vrow = VTp + ((size_t)((tok >> 10) * 16 + hc) * 64 + d0) * 1024 + (tok & 1023);
#pragma unroll
                for (int e = 0; e < 8; ++e) vrow[(size_t)e * 1024] = vv[e];
            }
        }
    }
}

// ---------------------------------------------------------------- LayerNorm
// v = xa + sum_p bf16 parts[p] + bias; out = LN(v)*g + beta.
__global__ __launch_bounds__(256) void ln_kernel(
    const float* __restrict__ xa, const short* __restrict__ parts, int nparts,
    const float* __restrict__ bias,
    const float* __restrict__ g, const float* __restrict__ beta,
    float* __restrict__ outf, short* __restrict__ outb)
{
    const int row = blockIdx.x;
    const int tid = threadIdx.x;
    float4 va = ((const float4*)(xa + (size_t)row * EE))[tid];
    float4 vb = ((const float4*)bias)[tid];
    float v0 = va.x + vb.x, v1 = va.y + vb.y, v2 = va.z + vb.z, v3 = va.w + vb.w;
#pragma unroll 4
    for (int p = 0; p < nparts; ++p) {
        unsigned long long u8 = ((const unsigned long long*)(parts + p * PSTR + (size_t)row * EE))[tid];
        v0 += bf2f((short)(u8 & 0xffff));
        v1 += bf2f((short)((u8 >> 16) & 0xffff));
        v2 += bf2f((short)((u8 >> 32) & 0xffff));
        v3 += bf2f((short)(u8 >> 48));
    }
    float s  = v0 + v1 + v2 + v3;
    float ss = v0 * v0 + v1 * v1 + v2 * v2 + v3 * v3;
#pragma unroll
    for (int o = 1; o < 64; o <<= 1) { s += __shfl_xor(s, o); ss += __shfl_xor(ss, o); }
    __shared__ float red[8];
    if ((tid & 63) == 0) { red[(tid >> 6) * 2] = s; red[(tid >> 6) * 2 + 1] = ss; }
    __syncthreads();
    s  = red[0] + red[2] + red[4] + red[6];
    ss = red[1] + red[3] + red[5] + red[7];
    float mean = s * (1.0f / EE);
    float var  = ss * (1.0f / EE) - mean * mean;
    float rstd = rsqrtf(var + 1e-5f);
    float4 vg = ((const float4*)g)[tid];
    float4 vt = ((const float4*)beta)[tid];
    float o0 = (v0 - mean) * rstd * vg.x + vt.x;
    float o1 = (v1 - mean) * rstd * vg.y + vt.y;
    float o2 = (v2 - mean) * rstd * vg.z + vt.z;
    float o3 = (v3 - mean) * rstd * vg.w + vt.w;
    if (outf) ((float4*)(outf + (size_t)row * EE))[tid] = make_float4(o0, o1, o2, o3);
    if (outb) {
        unsigned long long u =
              (unsigned long long)(unsigned short)f2bf(o0)
            | ((unsigned long long)(unsigned short)f2bf(o1) << 16)
            | ((unsigned long long)(unsigned short)f2bf(o2) << 32)
            | ((unsigned long long)(unsigned short)f2bf(o3) << 48);
        ((unsigned long long*)(outb + (size_t)row * EE))[tid] = u;
    }
}

// ---------------------------------------------------------------- attention (MFMA)
__global__ __launch_bounds__(256) void attn_mfma(
    const short* __restrict__ qkv,
    const short* __restrict__ vt,
    short* __restrict__ ctxp,
    short* __restrict__ pb)     // [b][i][h][272] bf16
{
    __shared__ float Sb[32 * 324];   // 41.5 KB
    __shared__ short Pl[32 * 322];   // 20.1 KB
    const int tid = threadIdx.x, wave = tid >> 6, lane = tid & 63;
    const int quad = lane >> 4, mcol = lane & 15;
    const int i0 = blockIdx.x * 32, h = blockIdx.y, b = blockIdx.z;
    const int jb0 = i0 - 128;

    const short* qb = qkv + (size_t)(b * 1024) * 3072 + h * 64;
    const short* kb = qb + 1024;

    short8 aq[2][2];
#pragma unroll
    for (int mt = 0; mt < 2; ++mt)
#pragma unroll
        for (int ks = 0; ks < 2; ++ks)
            aq[mt][ks] = *(const short8*)(qb + (size_t)(i0 + mt * 16 + mcol) * 3072 + ks * 32 + quad * 8);

    floatx4 sacc[2][5];
#pragma unroll
    for (int mt = 0; mt < 2; ++mt)
#pragma unroll
        for (int c = 0; c < 5; ++c) sacc[mt][c] = (floatx4){0.f, 0.f, 0.f, 0.f};

#pragma unroll
    for (int c = 0; c < 5; ++c) {
        int ct = c * 4 + wave;
        int j = jb0 + ct * 16 + mcol;
        j = min(max(j, 0), 1023);
        const short* kr = kb + (size_t)j * 3072 + quad * 8;
        short8 b0 = *(const short8*)kr;
        short8 b1 = *(const short8*)(kr + 32);
        sacc[0][c] = __builtin_amdgcn_mfma_f32_16x16x32_bf16(aq[0][0], b0, sacc[0][c], 0, 0, 0);
        sacc[1][c] = __builtin_amdgcn_mfma_f32_16x16x32_bf16(aq[1][0], b0, sacc[1][c], 0, 0, 0);
        sacc[0][c] = __builtin_amdgcn_mfma_f32_16x16x32_bf16(aq[0][1], b1, sacc[0][c], 0, 0, 0);
        sacc[1][c] = __builtin_amdgcn_mfma_f32_16x16x32_bf16(aq[1][1], b1, sacc[1][c], 0, 0, 0);
    }
#pragma unroll
    for (int mt = 0; mt < 2; ++mt)
#pragma unroll
        for (int c = 0; c < 5; ++c) {
            int jo = (c * 4 + wave) * 16 + mcol;
            int rowb = mt * 16 + quad * 4;
#pragma unroll
            for (int r = 0; r < 4; ++r)
                Sb[(rowb + r) * 324 + jo] = sacc[mt][c][r];
        }
    __syncthreads();

    for (int rr = 0; rr < 8; ++rr) {
        const int r = wave * 8 + rr;
        float sv[5];
#pragma unroll
        for (int t = 0; t < 5; ++t) {
            int jo = lane + t * 64;
            bool val = (jo >= r) && (jo <= r + 256) && ((unsigned)(jb0 + jo) < 1024u);
            sv[t] = val ? Sb[r * 324 + jo] * 0.125f : -1e30f;
        }
        float m = sv[0];
#pragma unroll
        for (int t = 1; t < 5; ++t) m = fmaxf(m, sv[t]);
#pragma unroll
        for (int o = 32; o; o >>= 1) m = fmaxf(m, __shfl_xor(m, o));
        float l = 0.f, p[5];
#pragma unroll
        for (int t = 0; t < 5; ++t) { p[t] = __expf(sv[t] - m); l += p[t]; }
#pragma unroll
        for (int o = 32; o; o >>= 1) l += __shfl_xor(l, o);
        float inv = 1.0f / l;
        short* pbrow = pb + ((size_t)(b * 1024 + i0 + r) * 16 + h) * 272;
#pragma unroll
        for (int t = 0; t < 5; ++t) {
            int jo = lane + t * 64;
            short pv = f2bf(p[t] * inv);
            Pl[r * 322 + jo] = pv;
            int jr = jo - r;
            if ((unsigned)jr < 272u) pbrow[jr] = pv;
        }
    }
    __syncthreads();

    const int mt = wave & 1, dt0 = (wave >> 1) * 2;
    floatx4 cacc[2];
    cacc[0] = (floatx4){0.f, 0.f, 0.f, 0.f};
    cacc[1] = (floatx4){0.f, 0.f, 0.f, 0.f};
    const short* vtb = vt + (size_t)((b * 16 + h) * 64) * 1024;
#pragma unroll
    for (int jc = 0; jc < 10; ++jc) {
        short8 ap = *(const short8*)&Pl[(mt * 16 + mcol) * 322 + jc * 32 + quad * 8];
        int jg = jb0 + jc * 32 + quad * 8;
        if ((unsigned)jg >= 1024u) jg = 0;
#pragma unroll
        for (int e = 0; e < 2; ++e) {
            short8 bv = *(const short8*)(vtb + (size_t)((dt0 + e) * 16 + mcol) * 1024 + jg);
            cacc[e] = __builtin_amdgcn_mfma_f32_16x16x32_bf16(ap, bv, cacc[e], 0, 0, 0);
        }
    }
#pragma unroll
    for (int e = 0; e < 2; ++e) {
        int col = h * 64 + (dt0 + e) * 16 + mcol;
#pragma unroll
        for (int r = 0; r < 4; ++r) {
            int row = i0 + mt * 16 + quad * 4 + r;
            ctxp[(size_t)(b * 1024 + row) * 1024 + col] = f2bf(cacc[e][r]);
        }
    }
}

// ---------------------------------------------------------------- head-mean reduce
__global__ __launch_bounds__(256) void pb_reduce(const short* __restrict__ pb,
                                                 float* __restrict__ aw)
{
    const int i = blockIdx.x & 1023, b = blockIdx.x >> 10;
    __shared__ short P[16 * 272];
    const unsigned* src = (const unsigned*)(pb + (size_t)(b * 1024 + i) * 16 * 272);
    for (int t = threadIdx.x; t < 16 * 272 / 2; t += 256)
        ((unsigned*)P)[t] = src[t];
    __syncthreads();
    float* row = aw + ((size_t)(b * 1024) + i) * 1024;
    for (int j = threadIdx.x; j < 1024; j += 256) {
        int jr = j - i + 128;
        float s = 0.f;
        if ((unsigned)jr < 272u) {
#pragma unroll
            for (int hh = 0; hh < 16; ++hh)
                s += bf2f(P[hh * 272 + jr]);
            s *= (1.0f / 16.0f);
        }
        row[j] = s;
    }
}

// ---------------------------------------------------------------- launch
extern "C" void kernel_launch(void* const* d_in, const int* in_sizes, int n_in,
                              void* d_out, int out_size, void* d_ws, size_t ws_size,
                              hipStream_t stream) {
    const float* x    = (const float*)d_in[0];
    const float* wqkv = (const float*)d_in[1];
    const float* bqkv = (const float*)d_in[2];
    const float* wo   = (const float*)d_in[3];
    const float* bo   = (const float*)d_in[4];
    const float* g1   = (const float*)d_in[5];
    const float* be1  = (const float*)d_in[6];
    const float* w1   = (const float*)d_in[7];
    const float* bb1  = (const float*)d_in[8];
    const float* w2   = (const float*)d_in[9];
    const float* bb2  = (const float*)d_in[10];
    const float* g2   = (const float*)d_in[11];
    const float* be2  = (const float*)d_in[12];

    char* ws = (char*)d_ws;
    size_t off = 0;
    auto take = [&](size_t bytes) {
        void* p = ws + off;
        off += (bytes + 255) & ~(size_t)255;
        return p;
    };
    short* xb     = (short*)take((size_t)4096 * 1024 * 2);
    short* wqkv_b = (short*)take((size_t)3072 * 1024 * 2);
    short* wo_b   = (short*)take((size_t)1024 * 1024 * 2);
    short* w1_b   = (short*)take((size_t)4096 * 1024 * 2);
    short* w2_b   = (short*)take((size_t)1024 * 4096 * 2);
    // qkv_b(25.2 MB) + ctx_b(8.4 MB) contiguous = 33.6 MB, reused as the 4
    // bf16 FFN2 split-K partials (lifetimes disjoint).
    short* qkv_b  = (short*)take((size_t)4096 * 3072 * 2);
    short* ctx_b  = (short*)take((size_t)4096 * 1024 * 2);
    short* ff2_p  = qkv_b;
    short* attn_p = (short*)take((size_t)2 * 4096 * 1024 * 2);  // out-proj bf16 partials x2
    float* h_f    = (float*)take((size_t)4096 * 1024 * 4);
    short* vt_ws  = (short*)h_f;                                // vt dead before ln1 writes h_f
    short* h_b    = (short*)take((size_t)4096 * 1024 * 2);
    short* pb_ws  = (short*)take((size_t)4 * 1024 * 16 * 272 * 2);  // 35.7 MB
    short* ff_b   = pb_ws;                                      // FFN1 out aliases pb (33.6 <= 35.7)

    float* out_f = (float*)d_out;
    float* attnW = (float*)d_out + (size_t)4 * 1024 * 1024;

    // bf16 conversions (single launch)
    cvt5<<<16384, 256, 0, stream>>>(x, wqkv, wo, w1, w2, xb, wqkv_b, wo_b, w1_b, w2_b);

    // qkv projection (also writes V transposed into vt_ws)
    gemm_bt<false, true, false><<<dim3(32, 24), 256, 0, stream>>>(
        xb, wqkv_b, bqkv, qkv_b, vt_ws, 4096, 3072, 1024, 1024);

    // banded attention (MFMA)
    attn_mfma<<<dim3(32, 16, 4), 256, 0, stream>>>(qkv_b, vt_ws, ctx_b, pb_ws);

    // head-mean attention weights
    pb_reduce<<<4096, 256, 0, stream>>>(pb_ws, attnW);

    // out projection, split-K=2 -> bf16 partials
    gemm_bt<false, false, true><<<dim3(32, 8, 2), 256, 0, stream>>>(
        ctx_b, wo_b, nullptr, attn_p, nullptr, 4096, 1024, 1024, 512);

    // h = LN(x + p0 + p1 + bo)
    ln_kernel<<<4096, 256, 0, stream>>>(x, attn_p, 2, bo, g1, be1, h_f, h_b);

    // FFN1 + ReLU -> bf16
    gemm_bt<true, false, false><<<dim3(32, 32), 256, 0, stream>>>(
        h_b, w1_b, bb1, ff_b, nullptr, 4096, 4096, 1024, 1024);

    // FFN2, split-K=4 -> bf16 partials
    gemm_bt<false, false, true><<<dim3(32, 8, 4), 256, 0, stream>>>(
        ff_b, w2_b, nullptr, ff2_p, nullptr, 4096, 1024, 4096, 1024);

    // out = LN(h + p0..p3 + bb2)
    ln_kernel<<<4096, 256, 0, stream>>>(h_f, ff2_p, 4, bb2, g2, be2, out_f, nullptr);
}

// Round 5
// 377.246 us; speedup vs baseline: 2.0346x; 1.0764x over previous
//
#include <hip/hip_runtime.h>

// Shapes fixed by setup_inputs(): B=4, L=1024, E=1024, H=16, D=64, W=128
#define BB 4
#define LL 1024
#define EE 1024
#define HH 16
#define DD 64

typedef __attribute__((ext_vector_type(8))) short short8;
typedef __attribute__((ext_vector_type(4))) float floatx4;

#define PSTR ((size_t)4096 * 1024)   // split-K partial stride (elements, bf16)

__device__ __forceinline__ float bf2f(short s) {
    union { unsigned u; float f; } c;
    c.u = ((unsigned)(unsigned short)s) << 16;
    return c.f;
}
__device__ __forceinline__ short f2bf(float f) {
    union { float f; unsigned u; } c; c.f = f;
    unsigned r = c.u + 0x7fffu + ((c.u >> 16) & 1u);
    return (short)(r >> 16);
}

__device__ __forceinline__ void async_copy16(const void* g, void* l) {
    __builtin_amdgcn_global_load_lds(
        (const __attribute__((address_space(1))) unsigned int*)g,
        (__attribute__((address_space(3))) unsigned int*)l, 16, 0, 0);
}

// ---------------------------------------------------------------- convert (all 5 tensors, one launch)
__global__ __launch_bounds__(256) void cvt5(
    const float* __restrict__ x, const float* __restrict__ wqkv,
    const float* __restrict__ wo, const float* __restrict__ w1,
    const float* __restrict__ w2,
    short* __restrict__ xb, short* __restrict__ wqkvb, short* __restrict__ wob,
    short* __restrict__ w1b, short* __restrict__ w2b)
{
    int bi = blockIdx.x;
    const float* in; short* out; int base;
    if      (bi <  4096) { in = x;    out = xb;    base = 0;     }
    else if (bi <  7168) { in = wqkv; out = wqkvb; base = 4096;  }
    else if (bi <  8192) { in = wo;   out = wob;   base = 7168;  }
    else if (bi < 12288) { in = w1;   out = w1b;   base = 8192;  }
    else                 { in = w2;   out = w2b;   base = 12288; }
    int i = (bi - base) * 256 + threadIdx.x;
    float4 v = ((const float4*)in)[i];
    unsigned long long u =
          (unsigned long long)(unsigned short)f2bf(v.x)
        | ((unsigned long long)(unsigned short)f2bf(v.y) << 16)
        | ((unsigned long long)(unsigned short)f2bf(v.z) << 32)
        | ((unsigned long long)(unsigned short)f2bf(v.w) << 48);
    ((unsigned long long*)out)[i] = u;
}

// ---------------------------------------------------------------- GEMM (NT)
// C[m,n] = sum_k A[m,k]*B[n,k] (+bias); 128x128 tile, BK=64, 256 thr.
// LDS k-chunk XOR swizzle: chunk g of row r lives at position g^(r&7), set up
// by permuting each DMA lane's global source chunk (LDS dest is lane-fixed).
// Frag ds_read_b128 then hits 8 bank-groups / 16 rows -> 2-way = free (m136).
// Output always bf16. SK: blockIdx.z selects K-split, out += z*PSTR, no bias.
// WVT: scatter cols>=2048 transposed into VTp[b][h][d][1024].
template<bool RELU, bool WVT, bool SK>
__global__ __launch_bounds__(256) void gemm_bt(
    const short* __restrict__ A, const short* __restrict__ Bw,
    const float* __restrict__ bias,
    short* __restrict__ Cb, short* __restrict__ VTp,
    int M, int N, int K, int Ksp)
{
    __shared__ union U {
        struct { short As[128 * 64]; short Bs[128 * 64]; } s;
        short Cs[128 * 136];
    } u;   // 34,816 B -> 4 blocks/CU (LDS-limited)
    const int tid  = threadIdx.x;
    const int wave = tid >> 6, lane = tid & 63;
    const int m0 = blockIdx.x * 128, n0 = blockIdx.y * 128;
    const int wm = (wave & 1) * 64, wn = (wave >> 1) * 64;
    const int kbase = SK ? blockIdx.z * Ksp : 0;

    floatx4 acc[4][4];
#pragma unroll
    for (int i = 0; i < 4; ++i)
#pragma unroll
        for (int j = 0; j < 4; ++j) acc[i][j] = (floatx4){0.f, 0.f, 0.f, 0.f};

    // staging: wave w covers rows {s*32 + w*8 + (lane>>3)}; global k-chunk is
    // XOR-permuted so LDS position (lane&7) holds chunk (lane&7)^(r&7).
    const int srow = wave * 8 + (lane >> 3);
    const int scol = (((lane & 7) ^ ((lane >> 3) & 7))) * 8;
    const short* gA = A  + (size_t)(m0 + srow) * K + kbase + scol;
    const short* gB = Bw + (size_t)(n0 + srow) * K + kbase + scol;
    short* lA = u.s.As + wave * 512;   // + s*2048; DMA adds lane*16B
    short* lB = u.s.Bs + wave * 512;

    const int fr = lane & 15, quad = lane >> 4;
    const int kiters = (SK ? Ksp : K) >> 6;
    for (int kt = 0; kt < kiters; ++kt) {
#pragma unroll
        for (int s = 0; s < 4; ++s) {
            async_copy16(gA + (size_t)s * 32 * K, lA + s * 2048);
            async_copy16(gB + (size_t)s * 32 * K, lB + s * 2048);
        }
        gA += 64; gB += 64;
        __syncthreads();
#pragma unroll
        for (int ks = 0; ks < 2; ++ks) {
            short8 af[4], bf[4];
#pragma unroll
            for (int i = 0; i < 4; ++i) {
                int pos = ((ks * 4 + quad) ^ (fr & 7)) * 8;   // swizzled chunk
                af[i] = *(const short8*)&u.s.As[(wm + i * 16 + fr) * 64 + pos];
                bf[i] = *(const short8*)&u.s.Bs[(wn + i * 16 + fr) * 64 + pos];
            }
#pragma unroll
            for (int i = 0; i < 4; ++i)
#pragma unroll
                for (int j = 0; j < 4; ++j)
                    acc[i][j] = __builtin_amdgcn_mfma_f32_16x16x32_bf16(af[i], bf[j], acc[i][j], 0, 0, 0);
        }
        __syncthreads();
    }

    // ---- epilogue: C-layout regs -> bf16 LDS tile (stride 136) ----
    const int cc = lane & 15;
    const int rb = (lane >> 4) * 4;
#pragma unroll
    for (int j = 0; j < 4; ++j) {
        int col = wn + j * 16 + cc;
        float bv = SK ? 0.0f : bias[n0 + col];
#pragma unroll
        for (int i = 0; i < 4; ++i) {
            int row = wm + i * 16 + rb;
#pragma unroll
            for (int r = 0; r < 4; ++r) {
                float v = acc[i][j][r] + bv;
                if (RELU) v = fmaxf(v, 0.0f);
                u.Cs[(row + r) * 136 + col] = f2bf(v);
            }
        }
    }
    __syncthreads();
    // ---- coalesced 16B stores ----
    short* Co = Cb + (SK ? (size_t)blockIdx.z * PSTR : 0);
    const int trow = tid >> 4, tcol = (tid & 15) * 8;
#pragma unroll
    for (int p = 0; p < 8; ++p) {
        int row = p * 16 + trow;
        short8 vv = *(const short8*)&u.Cs[row * 136 + tcol];
        *(short8*)&Co[(size_t)(m0 + row) * N + n0 + tcol] = vv;
        if (WVT) {
            int gc0 = n0 + tcol;
            if (gc0 >= 2048) {
                int tok = m0 + row;
                int hc = (gc0 - 2048) >> 6, d0 = (gc0 - 2048) & 63;
                short* vrow = VTp + ((size_t)((tok >> 10) * 16 + hc) * 64 + d0) * 1024 + (tok & 1023);
#pragma unroll
                for (int e = 0; e < 8; ++e) vrow[(size_t)e * 1024] = vv[e];
            }
        }
    }
}

// ---------------------------------------------------------------- LayerNorm
// v = xa + sum_p bf16 parts[p] + bias; out = LN(v)*g + beta.
__global__ __launch_bounds__(256) void ln_kernel(
    const float* __restrict__ xa, const short* __restrict__ parts, int nparts,
    const float* __restrict__ bias,
    const float* __restrict__ g, const float* __restrict__ beta,
    float* __restrict__ outf, short* __restrict__ outb)
{
    const int row = blockIdx.x;
    const int tid = threadIdx.x;
    float4 va = ((const float4*)(xa + (size_t)row * EE))[tid];
    float4 vb = ((const float4*)bias)[tid];
    float v0 = va.x + vb.x, v1 = va.y + vb.y, v2 = va.z + vb.z, v3 = va.w + vb.w;
#pragma unroll 4
    for (int p = 0; p < nparts; ++p) {
        unsigned long long u8 = ((const unsigned long long*)(parts + p * PSTR + (size_t)row * EE))[tid];
        v0 += bf2f((short)(u8 & 0xffff));
        v1 += bf2f((short)((u8 >> 16) & 0xffff));
        v2 += bf2f((short)((u8 >> 32) & 0xffff));
        v3 += bf2f((short)(u8 >> 48));
    }
    float s  = v0 + v1 + v2 + v3;
    float ss = v0 * v0 + v1 * v1 + v2 * v2 + v3 * v3;
#pragma unroll
    for (int o = 1; o < 64; o <<= 1) { s += __shfl_xor(s, o); ss += __shfl_xor(ss, o); }
    __shared__ float red[8];
    if ((tid & 63) == 0) { red[(tid >> 6) * 2] = s; red[(tid >> 6) * 2 + 1] = ss; }
    __syncthreads();
    s  = red[0] + red[2] + red[4] + red[6];
    ss = red[1] + red[3] + red[5] + red[7];
    float mean = s * (1.0f / EE);
    float var  = ss * (1.0f / EE) - mean * mean;
    float rstd = rsqrtf(var + 1e-5f);
    float4 vg = ((const float4*)g)[tid];
    float4 vt = ((const float4*)beta)[tid];
    float o0 = (v0 - mean) * rstd * vg.x + vt.x;
    float o1 = (v1 - mean) * rstd * vg.y + vt.y;
    float o2 = (v2 - mean) * rstd * vg.z + vt.z;
    float o3 = (v3 - mean) * rstd * vg.w + vt.w;
    if (outf) ((float4*)(outf + (size_t)row * EE))[tid] = make_float4(o0, o1, o2, o3);
    if (outb) {
        unsigned long long u =
              (unsigned long long)(unsigned short)f2bf(o0)
            | ((unsigned long long)(unsigned short)f2bf(o1) << 16)
            | ((unsigned long long)(unsigned short)f2bf(o2) << 32)
            | ((unsigned long long)(unsigned short)f2bf(o3) << 48);
        ((unsigned long long*)(outb + (size_t)row * EE))[tid] = u;
    }
}

// ---------------------------------------------------------------- attention (MFMA)
__global__ __launch_bounds__(256) void attn_mfma(
    const short* __restrict__ qkv,
    const short* __restrict__ vt,
    short* __restrict__ ctxp,
    short* __restrict__ pb)     // [b][i][h][272] bf16
{
    __shared__ float Sb[32 * 324];   // 41.5 KB
    __shared__ short Pl[32 * 322];   // 20.1 KB
    const int tid = threadIdx.x, wave = tid >> 6, lane = tid & 63;
    const int quad = lane >> 4, mcol = lane & 15;
    const int i0 = blockIdx.x * 32, h = blockIdx.y, b = blockIdx.z;
    const int jb0 = i0 - 128;

    const short* qb = qkv + (size_t)(b * 1024) * 3072 + h * 64;
    const short* kb = qb + 1024;

    short8 aq[2][2];
#pragma unroll
    for (int mt = 0; mt < 2; ++mt)
#pragma unroll
        for (int ks = 0; ks < 2; ++ks)
            aq[mt][ks] = *(const short8*)(qb + (size_t)(i0 + mt * 16 + mcol) * 3072 + ks * 32 + quad * 8);

    floatx4 sacc[2][5];
#pragma unroll
    for (int mt = 0; mt < 2; ++mt)
#pragma unroll
        for (int c = 0; c < 5; ++c) sacc[mt][c] = (floatx4){0.f, 0.f, 0.f, 0.f};

#pragma unroll
    for (int c = 0; c < 5; ++c) {
        int ct = c * 4 + wave;
        int j = jb0 + ct * 16 + mcol;
        j = min(max(j, 0), 1023);
        const short* kr = kb + (size_t)j * 3072 + quad * 8;
        short8 b0 = *(const short8*)kr;
        short8 b1 = *(const short8*)(kr + 32);
        sacc[0][c] = __builtin_amdgcn_mfma_f32_16x16x32_bf16(aq[0][0], b0, sacc[0][c], 0, 0, 0);
        sacc[1][c] = __builtin_amdgcn_mfma_f32_16x16x32_bf16(aq[1][0], b0, sacc[1][c], 0, 0, 0);
        sacc[0][c] = __builtin_amdgcn_mfma_f32_16x16x32_bf16(aq[0][1], b1, sacc[0][c], 0, 0, 0);
        sacc[1][c] = __builtin_amdgcn_mfma_f32_16x16x32_bf16(aq[1][1], b1, sacc[1][c], 0, 0, 0);
    }
#pragma unroll
    for (int mt = 0; mt < 2; ++mt)
#pragma unroll
        for (int c = 0; c < 5; ++c) {
            int jo = (c * 4 + wave) * 16 + mcol;
            int rowb = mt * 16 + quad * 4;
#pragma unroll
            for (int r = 0; r < 4; ++r)
                Sb[(rowb + r) * 324 + jo] = sacc[mt][c][r];
        }
    __syncthreads();

    for (int rr = 0; rr < 8; ++rr) {
        const int r = wave * 8 + rr;
        float sv[5];
#pragma unroll
        for (int t = 0; t < 5; ++t) {
            int jo = lane + t * 64;
            bool val = (jo >= r) && (jo <= r + 256) && ((unsigned)(jb0 + jo) < 1024u);
            sv[t] = val ? Sb[r * 324 + jo] * 0.125f : -1e30f;
        }
        float m = sv[0];
#pragma unroll
        for (int t = 1; t < 5; ++t) m = fmaxf(m, sv[t]);
#pragma unroll
        for (int o = 32; o; o >>= 1) m = fmaxf(m, __shfl_xor(m, o));
        float l = 0.f, p[5];
#pragma unroll
        for (int t = 0; t < 5; ++t) { p[t] = __expf(sv[t] - m); l += p[t]; }
#pragma unroll
        for (int o = 32; o; o >>= 1) l += __shfl_xor(l, o);
        float inv = 1.0f / l;
        short* pbrow = pb + ((size_t)(b * 1024 + i0 + r) * 16 + h) * 272;
#pragma unroll
        for (int t = 0; t < 5; ++t) {
            int jo = lane + t * 64;
            short pv = f2bf(p[t] * inv);
            Pl[r * 322 + jo] = pv;
            int jr = jo - r;
            if ((unsigned)jr < 272u) pbrow[jr] = pv;
        }
    }
    __syncthreads();

    const int mt = wave & 1, dt0 = (wave >> 1) * 2;
    floatx4 cacc[2];
    cacc[0] = (floatx4){0.f, 0.f, 0.f, 0.f};
    cacc[1] = (floatx4){0.f, 0.f, 0.f, 0.f};
    const short* vtb = vt + (size_t)((b * 16 + h) * 64) * 1024;
#pragma unroll
    for (int jc = 0; jc < 10; ++jc) {
        short8 ap = *(const short8*)&Pl[(mt * 16 + mcol) * 322 + jc * 32 + quad * 8];
        int jg = jb0 + jc * 32 + quad * 8;
        if ((unsigned)jg >= 1024u) jg = 0;
#pragma unroll
        for (int e = 0; e < 2; ++e) {
            short8 bv = *(const short8*)(vtb + (size_t)((dt0 + e) * 16 + mcol) * 1024 + jg);
            cacc[e] = __builtin_amdgcn_mfma_f32_16x16x32_bf16(ap, bv, cacc[e], 0, 0, 0);
        }
    }
#pragma unroll
    for (int e = 0; e < 2; ++e) {
        int col = h * 64 + (dt0 + e) * 16 + mcol;
#pragma unroll
        for (int r = 0; r < 4; ++r) {
            int row = i0 + mt * 16 + quad * 4 + r;
            ctxp[(size_t)(b * 1024 + row) * 1024 + col] = f2bf(cacc[e][r]);
        }
    }
}

// ---------------------------------------------------------------- head-mean reduce
__global__ __launch_bounds__(256) void pb_reduce(const short* __restrict__ pb,
                                                 float* __restrict__ aw)
{
    const int i = blockIdx.x & 1023, b = blockIdx.x >> 10;
    __shared__ short P[16 * 272];
    const unsigned* src = (const unsigned*)(pb + (size_t)(b * 1024 + i) * 16 * 272);
    for (int t = threadIdx.x; t < 16 * 272 / 2; t += 256)
        ((unsigned*)P)[t] = src[t];
    __syncthreads();
    float* row = aw + ((size_t)(b * 1024) + i) * 1024;
    for (int j = threadIdx.x; j < 1024; j += 256) {
        int jr = j - i + 128;
        float s = 0.f;
        if ((unsigned)jr < 272u) {
#pragma unroll
            for (int hh = 0; hh < 16; ++hh)
                s += bf2f(P[hh * 272 + jr]);
            s *= (1.0f / 16.0f);
        }
        row[j] = s;
    }
}

// ---------------------------------------------------------------- launch
extern "C" void kernel_launch(void* const* d_in, const int* in_sizes, int n_in,
                              void* d_out, int out_size, void* d_ws, size_t ws_size,
                              hipStream_t stream) {
    const float* x    = (const float*)d_in[0];
    const float* wqkv = (const float*)d_in[1];
    const float* bqkv = (const float*)d_in[2];
    const float* wo   = (const float*)d_in[3];
    const float* bo   = (const float*)d_in[4];
    const float* g1   = (const float*)d_in[5];
    const float* be1  = (const float*)d_in[6];
    const float* w1   = (const float*)d_in[7];
    const float* bb1  = (const float*)d_in[8];
    const float* w2   = (const float*)d_in[9];
    const float* bb2  = (const float*)d_in[10];
    const float* g2   = (const float*)d_in[11];
    const float* be2  = (const float*)d_in[12];

    char* ws = (char*)d_ws;
    size_t off = 0;
    auto take = [&](size_t bytes) {
        void* p = ws + off;
        off += (bytes + 255) & ~(size_t)255;
        return p;
    };
    short* xb     = (short*)take((size_t)4096 * 1024 * 2);
    short* wqkv_b = (short*)take((size_t)3072 * 1024 * 2);
    short* wo_b   = (short*)take((size_t)1024 * 1024 * 2);
    short* w1_b   = (short*)take((size_t)4096 * 1024 * 2);
    short* w2_b   = (short*)take((size_t)1024 * 4096 * 2);
    // qkv_b(25.2 MB) + ctx_b(8.4 MB) contiguous = 33.6 MB, reused as the 4
    // bf16 FFN2 split-K partials (lifetimes disjoint).
    short* qkv_b  = (short*)take((size_t)4096 * 3072 * 2);
    short* ctx_b  = (short*)take((size_t)4096 * 1024 * 2);
    short* ff2_p  = qkv_b;
    short* attn_p = (short*)take((size_t)2 * 4096 * 1024 * 2);  // out-proj bf16 partials x2
    float* h_f    = (float*)take((size_t)4096 * 1024 * 4);
    short* vt_ws  = (short*)h_f;                                // vt dead before ln1 writes h_f
    short* h_b    = (short*)take((size_t)4096 * 1024 * 2);
    short* pb_ws  = (short*)take((size_t)4 * 1024 * 16 * 272 * 2);  // 35.7 MB
    short* ff_b   = pb_ws;                                      // FFN1 out aliases pb (33.6 <= 35.7)

    float* out_f = (float*)d_out;
    float* attnW = (float*)d_out + (size_t)4 * 1024 * 1024;

    // bf16 conversions (single launch)
    cvt5<<<16384, 256, 0, stream>>>(x, wqkv, wo, w1, w2, xb, wqkv_b, wo_b, w1_b, w2_b);

    // qkv projection (also writes V transposed into vt_ws)
    gemm_bt<false, true, false><<<dim3(32, 24), 256, 0, stream>>>(
        xb, wqkv_b, bqkv, qkv_b, vt_ws, 4096, 3072, 1024, 1024);

    // banded attention (MFMA)
    attn_mfma<<<dim3(32, 16, 4), 256, 0, stream>>>(qkv_b, vt_ws, ctx_b, pb_ws);

    // head-mean attention weights
    pb_reduce<<<4096, 256, 0, stream>>>(pb_ws, attnW);

    // out projection, split-K=2 -> bf16 partials
    gemm_bt<false, false, true><<<dim3(32, 8, 2), 256, 0, stream>>>(
        ctx_b, wo_b, nullptr, attn_p, nullptr, 4096, 1024, 1024, 512);

    // h = LN(x + p0 + p1 + bo)
    ln_kernel<<<4096, 256, 0, stream>>>(x, attn_p, 2, bo, g1, be1, h_f, h_b);

    // FFN1 + ReLU -> bf16
    gemm_bt<true, false, false><<<dim3(32, 32), 256, 0, stream>>>(
        h_b, w1_b, bb1, ff_b, nullptr, 4096, 4096, 1024, 1024);

    // FFN2, split-K=4 -> bf16 partials
    gemm_bt<false, false, true><<<dim3(32, 8, 4), 256, 0, stream>>>(
        ff_b, w2_b, nullptr, ff2_p, nullptr, 4096, 1024, 4096, 1024);

    // out = LN(h + p0..p3 + bb2)
    ln_kernel<<<4096, 256, 0, stream>>>(h_f, ff2_p, 4, bb2, g2, be2, out_f, nullptr);
}

// Round 6
// 375.547 us; speedup vs baseline: 2.0438x; 1.0045x over previous
//
#include <hip/hip_runtime.h>

// Shapes fixed by setup_inputs(): B=4, L=1024, E=1024, H=16, D=64, W=128
#define BB 4
#define LL 1024
#define EE 1024
#define HH 16
#define DD 64

typedef __attribute__((ext_vector_type(8))) short short8;
typedef __attribute__((ext_vector_type(4))) float floatx4;

#define PSTR ((size_t)4096 * 1024)   // split-K partial stride (elements, bf16)

__device__ __forceinline__ float bf2f(short s) {
    union { unsigned u; float f; } c;
    c.u = ((unsigned)(unsigned short)s) << 16;
    return c.f;
}
__device__ __forceinline__ short f2bf(float f) {
    union { float f; unsigned u; } c; c.f = f;
    unsigned r = c.u + 0x7fffu + ((c.u >> 16) & 1u);
    return (short)(r >> 16);
}

__device__ __forceinline__ void async_copy16(const void* g, void* l) {
    __builtin_amdgcn_global_load_lds(
        (const __attribute__((address_space(1))) unsigned int*)g,
        (__attribute__((address_space(3))) unsigned int*)l, 16, 0, 0);
}

// ---------------------------------------------------------------- convert (all 5 tensors, one launch)
__global__ __launch_bounds__(256) void cvt5(
    const float* __restrict__ x, const float* __restrict__ wqkv,
    const float* __restrict__ wo, const float* __restrict__ w1,
    const float* __restrict__ w2,
    short* __restrict__ xb, short* __restrict__ wqkvb, short* __restrict__ wob,
    short* __restrict__ w1b, short* __restrict__ w2b)
{
    int bi = blockIdx.x;
    const float* in; short* out; int base;
    if      (bi <  4096) { in = x;    out = xb;    base = 0;     }
    else if (bi <  7168) { in = wqkv; out = wqkvb; base = 4096;  }
    else if (bi <  8192) { in = wo;   out = wob;   base = 7168;  }
    else if (bi < 12288) { in = w1;   out = w1b;   base = 8192;  }
    else                 { in = w2;   out = w2b;   base = 12288; }
    int i = (bi - base) * 256 + threadIdx.x;
    float4 v = ((const float4*)in)[i];
    unsigned long long u =
          (unsigned long long)(unsigned short)f2bf(v.x)
        | ((unsigned long long)(unsigned short)f2bf(v.y) << 16)
        | ((unsigned long long)(unsigned short)f2bf(v.z) << 32)
        | ((unsigned long long)(unsigned short)f2bf(v.w) << 48);
    ((unsigned long long*)out)[i] = u;
}

// ---------------------------------------------------------------- GEMM (NT)
// C[m,n] = sum_k A[m,k]*B[n,k] (+bias); 128x128 tile, BK=64, 256 thr.
// LDS k-chunk XOR swizzle (chunk g of row r at g^(r&7)) -> conflict-free frags.
template<bool RELU, bool WVT, bool SK>
__global__ __launch_bounds__(256) void gemm_bt(
    const short* __restrict__ A, const short* __restrict__ Bw,
    const float* __restrict__ bias,
    short* __restrict__ Cb, short* __restrict__ VTp,
    int M, int N, int K, int Ksp)
{
    __shared__ union U {
        struct { short As[128 * 64]; short Bs[128 * 64]; } s;
        short Cs[128 * 136];
    } u;   // 34,816 B -> 4 blocks/CU (LDS-limited)
    const int tid  = threadIdx.x;
    const int wave = tid >> 6, lane = tid & 63;
    const int m0 = blockIdx.x * 128, n0 = blockIdx.y * 128;
    const int wm = (wave & 1) * 64, wn = (wave >> 1) * 64;
    const int kbase = SK ? blockIdx.z * Ksp : 0;

    floatx4 acc[4][4];
#pragma unroll
    for (int i = 0; i < 4; ++i)
#pragma unroll
        for (int j = 0; j < 4; ++j) acc[i][j] = (floatx4){0.f, 0.f, 0.f, 0.f};

    const int srow = wave * 8 + (lane >> 3);
    const int scol = (((lane & 7) ^ ((lane >> 3) & 7))) * 8;
    const short* gA = A  + (size_t)(m0 + srow) * K + kbase + scol;
    const short* gB = Bw + (size_t)(n0 + srow) * K + kbase + scol;
    short* lA = u.s.As + wave * 512;
    short* lB = u.s.Bs + wave * 512;

    const int fr = lane & 15, quad = lane >> 4;
    const int kiters = (SK ? Ksp : K) >> 6;
    for (int kt = 0; kt < kiters; ++kt) {
#pragma unroll
        for (int s = 0; s < 4; ++s) {
            async_copy16(gA + (size_t)s * 32 * K, lA + s * 2048);
            async_copy16(gB + (size_t)s * 32 * K, lB + s * 2048);
        }
        gA += 64; gB += 64;
        __syncthreads();
#pragma unroll
        for (int ks = 0; ks < 2; ++ks) {
            short8 af[4], bf[4];
#pragma unroll
            for (int i = 0; i < 4; ++i) {
                int pos = ((ks * 4 + quad) ^ (fr & 7)) * 8;
                af[i] = *(const short8*)&u.s.As[(wm + i * 16 + fr) * 64 + pos];
                bf[i] = *(const short8*)&u.s.Bs[(wn + i * 16 + fr) * 64 + pos];
            }
#pragma unroll
            for (int i = 0; i < 4; ++i)
#pragma unroll
                for (int j = 0; j < 4; ++j)
                    acc[i][j] = __builtin_amdgcn_mfma_f32_16x16x32_bf16(af[i], bf[j], acc[i][j], 0, 0, 0);
        }
        __syncthreads();
    }

    const int cc = lane & 15;
    const int rb = (lane >> 4) * 4;
#pragma unroll
    for (int j = 0; j < 4; ++j) {
        int col = wn + j * 16 + cc;
        float bv = SK ? 0.0f : bias[n0 + col];
#pragma unroll
        for (int i = 0; i < 4; ++i) {
            int row = wm + i * 16 + rb;
#pragma unroll
            for (int r = 0; r < 4; ++r) {
                float v = acc[i][j][r] + bv;
                if (RELU) v = fmaxf(v, 0.0f);
                u.Cs[(row + r) * 136 + col] = f2bf(v);
            }
        }
    }
    __syncthreads();
    short* Co = Cb + (SK ? (size_t)blockIdx.z * PSTR : 0);
    const int trow = tid >> 4, tcol = (tid & 15) * 8;
#pragma unroll
    for (int p = 0; p < 8; ++p) {
        int row = p * 16 + trow;
        short8 vv = *(const short8*)&u.Cs[row * 136 + tcol];
        *(short8*)&Co[(size_t)(m0 + row) * N + n0 + tcol] = vv;
        if (WVT) {
            int gc0 = n0 + tcol;
            if (gc0 >= 2048) {
                int tok = m0 + row;
                int hc = (gc0 - 2048) >> 6, d0 = (gc0 - 2048) & 63;
                short* vrow = VTp + ((size_t)((tok >> 10) * 16 + hc) * 64 + d0) * 1024 + (tok & 1023);
#pragma unroll
                for (int e = 0; e < 8; ++e) vrow[(size_t)e * 1024] = vv[e];
            }
        }
    }
}

// ---------------------------------------------------------------- LayerNorm
__global__ __launch_bounds__(256) void ln_kernel(
    const float* __restrict__ xa, const short* __restrict__ parts, int nparts,
    const float* __restrict__ bias,
    const float* __restrict__ g, const float* __restrict__ beta,
    float* __restrict__ outf, short* __restrict__ outb)
{
    const int row = blockIdx.x;
    const int tid = threadIdx.x;
    float4 va = ((const float4*)(xa + (size_t)row * EE))[tid];
    float4 vb = ((const float4*)bias)[tid];
    float v0 = va.x + vb.x, v1 = va.y + vb.y, v2 = va.z + vb.z, v3 = va.w + vb.w;
#pragma unroll 4
    for (int p = 0; p < nparts; ++p) {
        unsigned long long u8 = ((const unsigned long long*)(parts + p * PSTR + (size_t)row * EE))[tid];
        v0 += bf2f((short)(u8 & 0xffff));
        v1 += bf2f((short)((u8 >> 16) & 0xffff));
        v2 += bf2f((short)((u8 >> 32) & 0xffff));
        v3 += bf2f((short)(u8 >> 48));
    }
    float s  = v0 + v1 + v2 + v3;
    float ss = v0 * v0 + v1 * v1 + v2 * v2 + v3 * v3;
#pragma unroll
    for (int o = 1; o < 64; o <<= 1) { s += __shfl_xor(s, o); ss += __shfl_xor(ss, o); }
    __shared__ float red[8];
    if ((tid & 63) == 0) { red[(tid >> 6) * 2] = s; red[(tid >> 6) * 2 + 1] = ss; }
    __syncthreads();
    s  = red[0] + red[2] + red[4] + red[6];
    ss = red[1] + red[3] + red[5] + red[7];
    float mean = s * (1.0f / EE);
    float var  = ss * (1.0f / EE) - mean * mean;
    float rstd = rsqrtf(var + 1e-5f);
    float4 vg = ((const float4*)g)[tid];
    float4 vt = ((const float4*)beta)[tid];
    float o0 = (v0 - mean) * rstd * vg.x + vt.x;
    float o1 = (v1 - mean) * rstd * vg.y + vt.y;
    float o2 = (v2 - mean) * rstd * vg.z + vt.z;
    float o3 = (v3 - mean) * rstd * vg.w + vt.w;
    if (outf) ((float4*)(outf + (size_t)row * EE))[tid] = make_float4(o0, o1, o2, o3);
    if (outb) {
        unsigned long long u =
              (unsigned long long)(unsigned short)f2bf(o0)
            | ((unsigned long long)(unsigned short)f2bf(o1) << 16)
            | ((unsigned long long)(unsigned short)f2bf(o2) << 32)
            | ((unsigned long long)(unsigned short)f2bf(o3) << 48);
        ((unsigned long long*)(outb + (size_t)row * EE))[tid] = u;
    }
}

// ---------------------------------------------------------------- attention (MFMA, register softmax)
// 512 thr / 8 waves; block = (i-tile 32, h, b) via flat id (i0 slow for L2).
// QK: wave = (mt = w>>2, quarter = w&3); each wave 5 col-tiles (80 cols).
// Row softmax: quad shuffles (16-lane) + 1KB LDS cross-quarter combine.
// P -> Pl (XOR-swizzled, stride 320) ; PV: wave = (mt = w&1, dt = w>>1).
__global__ __launch_bounds__(512, 8) void attn_mfma(
    const short* __restrict__ qkv,
    const short* __restrict__ vt,
    short* __restrict__ ctxp,
    short* __restrict__ pb)     // [b][i][h][272] bf16
{
    __shared__ short Pl[32 * 320];   // 20,480 B
    __shared__ float Red[4][2][32];  //  1,024 B
    const int tid = threadIdx.x, wave = tid >> 6, lane = tid & 63;
    const int quad = lane >> 4, mcol = lane & 15;
    const int id = blockIdx.x;
    const int i0 = (id >> 6) * 32, h = id & 15, b = (id >> 4) & 3;
    const int jb0 = i0 - 128;

    const short* qb = qkv + (size_t)(b * 1024) * 3072 + h * 64;
    const short* kb = qb + 1024;

    // ---- QK^T ----
    const int mt = wave >> 2, qtr = wave & 3;
    const short* qrow = qb + (size_t)(i0 + mt * 16 + mcol) * 3072 + quad * 8;
    short8 aq0 = *(const short8*)qrow;
    short8 aq1 = *(const short8*)(qrow + 32);

    floatx4 sacc[5];
#pragma unroll
    for (int c = 0; c < 5; ++c) sacc[c] = (floatx4){0.f, 0.f, 0.f, 0.f};
#pragma unroll
    for (int c = 0; c < 5; ++c) {
        int j = jb0 + (qtr * 5 + c) * 16 + mcol;
        j = min(max(j, 0), 1023);
        const short* kr = kb + (size_t)j * 3072 + quad * 8;
        short8 b0 = *(const short8*)kr;
        short8 b1 = *(const short8*)(kr + 32);
        sacc[c] = __builtin_amdgcn_mfma_f32_16x16x32_bf16(aq0, b0, sacc[c], 0, 0, 0);
        sacc[c] = __builtin_amdgcn_mfma_f32_16x16x32_bf16(aq1, b1, sacc[c], 0, 0, 0);
    }

    // ---- mask+scale, quarter row-max (quad shuffles) ----
    const int row0 = mt * 16 + quad * 4;
#pragma unroll
    for (int r = 0; r < 4; ++r) {
        int row = row0 + r;
        float m = -1e30f;
#pragma unroll
        for (int c = 0; c < 5; ++c) {
            int jo = (qtr * 5 + c) * 16 + mcol;
            bool val = (jo >= row) && (jo <= row + 256) && ((unsigned)(jb0 + jo) < 1024u);
            float s = val ? sacc[c][r] * 0.125f : -1e30f;
            sacc[c][r] = s;
            m = fmaxf(m, s);
        }
        m = fmaxf(m, __shfl_xor(m, 1));
        m = fmaxf(m, __shfl_xor(m, 2));
        m = fmaxf(m, __shfl_xor(m, 4));
        m = fmaxf(m, __shfl_xor(m, 8));
        if (mcol == 0) Red[qtr][0][row] = m;
    }
    __syncthreads();
    // ---- exp + quarter row-sum ----
#pragma unroll
    for (int r = 0; r < 4; ++r) {
        int row = row0 + r;
        float M = fmaxf(fmaxf(Red[0][0][row], Red[1][0][row]),
                        fmaxf(Red[2][0][row], Red[3][0][row]));
        float l = 0.f;
#pragma unroll
        for (int c = 0; c < 5; ++c) {
            float p = __expf(sacc[c][r] - M);
            sacc[c][r] = p;
            l += p;
        }
        l += __shfl_xor(l, 1);
        l += __shfl_xor(l, 2);
        l += __shfl_xor(l, 4);
        l += __shfl_xor(l, 8);
        if (mcol == 0) Red[qtr][1][row] = l;
    }
    __syncthreads();
    // ---- normalize, write P (swizzled LDS) + pb (global) ----
#pragma unroll
    for (int r = 0; r < 4; ++r) {
        int row = row0 + r;
        float inv = 1.0f / (Red[0][1][row] + Red[1][1][row] +
                            Red[2][1][row] + Red[3][1][row]);
        short* pbrow = pb + ((size_t)(b * 1024 + i0 + row) * 16 + h) * 272;
#pragma unroll
        for (int c = 0; c < 5; ++c) {
            int jo = (qtr * 5 + c) * 16 + mcol;
            short pv = f2bf(sacc[c][r] * inv);
            Pl[row * 320 + (((jo >> 3) ^ (row & 7)) * 8) + (jo & 7)] = pv;
            int jr = jo - row;
            if ((unsigned)jr < 272u) pbrow[jr] = pv;
        }
    }
    __syncthreads();

    // ---- PV ----
    const int pmt = wave & 1, dt = wave >> 1;   // dt 0..3
    floatx4 cacc = (floatx4){0.f, 0.f, 0.f, 0.f};
    const short* vrow = vt + ((size_t)((b * 16 + h) * 64) + dt * 16 + mcol) * 1024;
    const int prow = (pmt * 16 + mcol) * 320;
#pragma unroll
    for (int jc = 0; jc < 10; ++jc) {
        short8 ap = *(const short8*)&Pl[prow + (((jc * 4 + quad) ^ (mcol & 7)) * 8)];
        int jg = jb0 + jc * 32 + quad * 8;
        if ((unsigned)jg >= 1024u) jg = 0;    // fully-masked frag (P=0)
        short8 bv = *(const short8*)(vrow + jg);
        cacc = __builtin_amdgcn_mfma_f32_16x16x32_bf16(ap, bv, cacc, 0, 0, 0);
    }
    int col = h * 64 + dt * 16 + mcol;
#pragma unroll
    for (int r = 0; r < 4; ++r) {
        int row = i0 + pmt * 16 + quad * 4 + r;
        ctxp[(size_t)(b * 1024 + row) * 1024 + col] = f2bf(cacc[r]);
    }
}

// ---------------------------------------------------------------- head-mean reduce
__global__ __launch_bounds__(256) void pb_reduce(const short* __restrict__ pb,
                                                 float* __restrict__ aw)
{
    const int i = blockIdx.x & 1023, b = blockIdx.x >> 10;
    __shared__ short P[16 * 272];
    const unsigned* src = (const unsigned*)(pb + (size_t)(b * 1024 + i) * 16 * 272);
    for (int t = threadIdx.x; t < 16 * 272 / 2; t += 256)
        ((unsigned*)P)[t] = src[t];
    __syncthreads();
    float* row = aw + ((size_t)(b * 1024) + i) * 1024;
    for (int j = threadIdx.x; j < 1024; j += 256) {
        int jr = j - i + 128;
        float s = 0.f;
        if ((unsigned)jr < 272u) {
#pragma unroll
            for (int hh = 0; hh < 16; ++hh)
                s += bf2f(P[hh * 272 + jr]);
            s *= (1.0f / 16.0f);
        }
        row[j] = s;
    }
}

// ---------------------------------------------------------------- launch
extern "C" void kernel_launch(void* const* d_in, const int* in_sizes, int n_in,
                              void* d_out, int out_size, void* d_ws, size_t ws_size,
                              hipStream_t stream) {
    const float* x    = (const float*)d_in[0];
    const float* wqkv = (const float*)d_in[1];
    const float* bqkv = (const float*)d_in[2];
    const float* wo   = (const float*)d_in[3];
    const float* bo   = (const float*)d_in[4];
    const float* g1   = (const float*)d_in[5];
    const float* be1  = (const float*)d_in[6];
    const float* w1   = (const float*)d_in[7];
    const float* bb1  = (const float*)d_in[8];
    const float* w2   = (const float*)d_in[9];
    const float* bb2  = (const float*)d_in[10];
    const float* g2   = (const float*)d_in[11];
    const float* be2  = (const float*)d_in[12];

    char* ws = (char*)d_ws;
    size_t off = 0;
    auto take = [&](size_t bytes) {
        void* p = ws + off;
        off += (bytes + 255) & ~(size_t)255;
        return p;
    };
    short* xb     = (short*)take((size_t)4096 * 1024 * 2);
    short* wqkv_b = (short*)take((size_t)3072 * 1024 * 2);
    short* wo_b   = (short*)take((size_t)1024 * 1024 * 2);
    short* w1_b   = (short*)take((size_t)4096 * 1024 * 2);
    short* w2_b   = (short*)take((size_t)1024 * 4096 * 2);
    short* qkv_b  = (short*)take((size_t)4096 * 3072 * 2);
    short* ctx_b  = (short*)take((size_t)4096 * 1024 * 2);
    short* ff2_p  = qkv_b;                                      // FFN2 bf16 partials x4
    short* attn_p = (short*)take((size_t)2 * 4096 * 1024 * 2);  // out-proj bf16 partials x2
    float* h_f    = (float*)take((size_t)4096 * 1024 * 4);
    short* vt_ws  = (short*)h_f;                                // vt dead before ln1 writes h_f
    short* h_b    = (short*)take((size_t)4096 * 1024 * 2);
    short* pb_ws  = (short*)take((size_t)4 * 1024 * 16 * 272 * 2);  // 35.7 MB
    short* ff_b   = pb_ws;                                      // FFN1 out aliases pb

    float* out_f = (float*)d_out;
    float* attnW = (float*)d_out + (size_t)4 * 1024 * 1024;

    // bf16 conversions (single launch)
    cvt5<<<16384, 256, 0, stream>>>(x, wqkv, wo, w1, w2, xb, wqkv_b, wo_b, w1_b, w2_b);

    // qkv projection (also writes V transposed into vt_ws)
    gemm_bt<false, true, false><<<dim3(32, 24), 256, 0, stream>>>(
        xb, wqkv_b, bqkv, qkv_b, vt_ws, 4096, 3072, 1024, 1024);

    // banded attention (MFMA, register softmax); flat grid, i0 slow
    attn_mfma<<<2048, 512, 0, stream>>>(qkv_b, vt_ws, ctx_b, pb_ws);

    // head-mean attention weights
    pb_reduce<<<4096, 256, 0, stream>>>(pb_ws, attnW);

    // out projection, split-K=2 -> bf16 partials
    gemm_bt<false, false, true><<<dim3(32, 8, 2), 256, 0, stream>>>(
        ctx_b, wo_b, nullptr, attn_p, nullptr, 4096, 1024, 1024, 512);

    // h = LN(x + p0 + p1 + bo)
    ln_kernel<<<4096, 256, 0, stream>>>(x, attn_p, 2, bo, g1, be1, h_f, h_b);

    // FFN1 + ReLU -> bf16
    gemm_bt<true, false, false><<<dim3(32, 32), 256, 0, stream>>>(
        h_b, w1_b, bb1, ff_b, nullptr, 4096, 4096, 1024, 1024);

    // FFN2, split-K=4 -> bf16 partials
    gemm_bt<false, false, true><<<dim3(32, 8, 4), 256, 0, stream>>>(
        ff_b, w2_b, nullptr, ff2_p, nullptr, 4096, 1024, 4096, 1024);

    // out = LN(h + p0..p3 + bb2)
    ln_kernel<<<4096, 256, 0, stream>>>(h_f, ff2_p, 4, bb2, g2, be2, out_f, nullptr);
}